// Round 16
// baseline (522.304 us; speedup 1.0000x reference)
//
#include <hip/hip_runtime.h>

typedef __attribute__((ext_vector_type(8))) short short8v;
typedef __attribute__((ext_vector_type(8))) unsigned short ushort8v;
typedef __attribute__((ext_vector_type(4))) unsigned short ushort4v;
typedef __attribute__((ext_vector_type(4))) float f32x4;

__device__ __forceinline__ unsigned short f2b(float f) {
  unsigned int u = __float_as_uint(f);
  unsigned int r = (u + 0x7FFFu + ((u >> 16) & 1u)) >> 16;
  return (unsigned short)r;
}
__device__ __forceinline__ float b2f(unsigned short h) {
  return __uint_as_float(((unsigned int)h) << 16);
}
__device__ __forceinline__ float gelu_f(float x) {
  float z = 0.7978845608028654f * (x + 0.044715f * x * x * x);
  float e = __expf(2.0f * z);
  float t = 1.0f - 2.0f / (e + 1.0f);
  return 0.5f * x * (1.0f + t);
}
// bijective XCD swizzle (m204)
__device__ __forceinline__ int xcd_swz(int wgid, int nwg) {
  int q = nwg >> 3, r = nwg & 7;
  int xcd = wgid & 7, idx = wgid >> 3;
  return (xcd < r ? xcd * (q + 1) : r * (q + 1) + (xcd - r) * q) + idx;
}
// 2D XCD region mapping (fc FETCH 69.9->41.2 MB measured)
__device__ __forceinline__ void map_tile(int wgid, int nwg, int nbx, int& tm, int& tn) {
  int nby = nwg / nbx;
  if ((nwg & 7) == 0 && (nby & 3) == 0 && (nbx & 1) == 0) {
    int x = wgid & 7, idx = wgid >> 3;
    int rh = nby >> 2, rw = nbx >> 1;
    int xr = x >> 1, xc = x & 1;
    tm = xr * rh + idx / rw;
    tn = xc * rw + idx % rw;
  } else {
    int swz = xcd_swz(wgid, nwg);
    tm = swz / nbx;
    tn = swz % nbx;
  }
}

// ---------------- enc f32 -> bf16 (weight transposes eliminated) ----------------
__global__ __launch_bounds__(256) void k_enccvt(const float* __restrict__ enc,
                                                unsigned short* __restrict__ encb) {
  size_t i = ((size_t)blockIdx.x * 256 + threadIdx.x) * 4;
  f32x4 v = *(const f32x4*)&enc[i];
  ushort4v o;
#pragma unroll
  for (int j = 0; j < 4; ++j) o[j] = f2b(v[j]);
  *(ushort4v*)&encb[i] = o;
}

// ---------------- LayerNorm over C=1024, out bf16 ----------------
__global__ __launch_bounds__(256) void k_ln(const float* __restrict__ in,
                                            const float* __restrict__ g,
                                            const float* __restrict__ b,
                                            unsigned short* __restrict__ out) {
  int row = blockIdx.x;
  const float* x = in + (size_t)row * 1024;
  int t = threadIdx.x;
  float v0 = x[t], v1 = x[t + 256], v2 = x[t + 512], v3 = x[t + 768];
  float s = v0 + v1 + v2 + v3;
  float s2 = v0 * v0 + v1 * v1 + v2 * v2 + v3 * v3;
#pragma unroll
  for (int m = 1; m < 64; m <<= 1) { s += __shfl_xor(s, m); s2 += __shfl_xor(s2, m); }
  __shared__ float rs[4], rs2[4];
  int w = t >> 6;
  if ((t & 63) == 0) { rs[w] = s; rs2[w] = s2; }
  __syncthreads();
  s = rs[0] + rs[1] + rs[2] + rs[3];
  s2 = rs2[0] + rs2[1] + rs2[2] + rs2[3];
  float mean = s * (1.0f / 1024.0f);
  float var = s2 * (1.0f / 1024.0f) - mean * mean;
  float rinv = rsqrtf(var + 1e-5f);
  unsigned short* o = out + (size_t)row * 1024;
  o[t]       = f2b((v0 - mean) * rinv * g[t]       + b[t]);
  o[t + 256] = f2b((v1 - mean) * rinv * g[t + 256] + b[t + 256]);
  o[t + 512] = f2b((v2 - mean) * rinv * g[t + 512] + b[t + 512]);
  o[t + 768] = f2b((v3 - mean) * rinv * g[t + 768] + b[t + 768]);
}

// ---------------- 128x128 GEMM: A bf16 [M][K], B DIRECT from f32 [K][N] ----------------
// B staged per thread as 32 column-strided dword loads (coalesced across lanes per k-row),
// held raw f32 through COMPUTE, converted (f2b, bit-identical to old wprep) at ds_write.
// Double-buffered 64KB LDS, prefetch distance 1, one barrier per K-tile (R9 structure).
// XOR swizzle: row r, 16B-chunk c at slot c^(r&7) (write & read; 0 conflicts measured).
template <bool GELU, bool WF32, bool WBF16, int NRES, bool RES1B>
__global__ __launch_bounds__(256, 2) void k_gf(
    const unsigned short* __restrict__ A, int lda,
    const float* __restrict__ W, int ldw,
    const float* __restrict__ bias,
    const float* __restrict__ res1, const unsigned short* __restrict__ res1b,
    const float* __restrict__ res2,
    float* __restrict__ outF, unsigned short* __restrict__ outB,
    int M, int N, int K, int nbx) {
  __shared__ unsigned short lds[32768];   // 2 bufs x {A 8192, B 8192} u16
  const int t = threadIdx.x;
  int tm, tn;
  map_tile(blockIdx.x, gridDim.x, nbx, tm, tn);
  const int tileM = tm * 128, tileN = tn * 128;
  const int lane = t & 63, w = t >> 6;
  const int wm = (w >> 1) * 64, wn = (w & 1) * 64;
  const int lr16 = lane & 15, kc4 = lane >> 4;

  // A staging: row sr (2 threads/row), half hb
  const int sr = t >> 1, hb = t & 1;
  int gr = tileM + sr; if (gr >= M) gr = M - 1;
  const unsigned short* ga = A + (size_t)gr * lda + hb * 32;
  unsigned short* const wA = &lds[sr * 64];
  const int wslA[4] = {((hb * 4 + 0) ^ (sr & 7)) * 8, ((hb * 4 + 1) ^ (sr & 7)) * 8,
                       ((hb * 4 + 2) ^ (sr & 7)) * 8, ((hb * 4 + 3) ^ (sr & 7)) * 8};
  // B staging: column bn (f32, stride ldw), k-group kg (32 k's)
  const int bn = t & 127, kg = t >> 7;
  const float* gwf = W + tileN + bn;
  unsigned short* const wB = &lds[8192 + bn * 64];
  const int wslB[4] = {((kg * 4 + 0) ^ (bn & 7)) * 8, ((kg * 4 + 1) ^ (bn & 7)) * 8,
                       ((kg * 4 + 2) ^ (bn & 7)) * 8, ((kg * 4 + 3) ^ (bn & 7)) * 8};

  f32x4 acc[4][4];
#pragma unroll
  for (int i = 0; i < 4; ++i)
#pragma unroll
    for (int j = 0; j < 4; ++j) acc[i][j] = f32x4{0.f, 0.f, 0.f, 0.f};

  const int nt = K >> 6;
  ushort8v ra[4];
  float fb[32];

#define LOADT(T)                                                              \
  do {                                                                        \
    size_t ko = (size_t)(T) << 6;                                             \
    _Pragma("unroll") for (int j = 0; j < 4; ++j)                             \
      ra[j] = *(const ushort8v*)(ga + ko + j * 8);                            \
    size_t kb = (ko + kg * 32) * (size_t)ldw;                                 \
    _Pragma("unroll") for (int j = 0; j < 32; ++j)                            \
      fb[j] = gwf[kb + (size_t)j * ldw];                                      \
    __builtin_amdgcn_sched_barrier(0);                                        \
  } while (0)
#define WRITET(bsel)                                                          \
  do {                                                                        \
    unsigned short* dA = wA + (bsel) * 16384;                                 \
    _Pragma("unroll") for (int j = 0; j < 4; ++j)                             \
      *(ushort8v*)(dA + wslA[j]) = ra[j];                                     \
    unsigned short* dB = wB + (bsel) * 16384;                                 \
    _Pragma("unroll") for (int c = 0; c < 4; ++c) {                           \
      ushort8v v;                                                             \
      _Pragma("unroll") for (int e = 0; e < 8; ++e) v[e] = f2b(fb[c * 8 + e]);\
      *(ushort8v*)(dB + wslB[c]) = v;                                         \
    }                                                                         \
  } while (0)
#define COMPUTE(bsel)                                                           \
  do {                                                                          \
    const int base = (bsel) * 16384;                                            \
    _Pragma("unroll") for (int ks = 0; ks < 2; ++ks) {                          \
      short8v bfr[4];                                                           \
      _Pragma("unroll") for (int n = 0; n < 4; ++n) {                           \
        int r = wn + n * 16 + lr16;                                             \
        int sl = ((ks * 4 + kc4) ^ (r & 7)) * 8;                                \
        bfr[n] = *(const short8v*)&lds[base + 8192 + r * 64 + sl];              \
      }                                                                         \
      _Pragma("unroll") for (int mi = 0; mi < 4; ++mi) {                        \
        int r = wm + mi * 16 + lr16;                                            \
        int sl = ((ks * 4 + kc4) ^ (r & 7)) * 8;                                \
        short8v af = *(const short8v*)&lds[base + r * 64 + sl];                 \
        _Pragma("unroll") for (int n = 0; n < 4; ++n)                           \
          acc[mi][n] =                                                          \
              __builtin_amdgcn_mfma_f32_16x16x32_bf16(af, bfr[n], acc[mi][n], 0, 0, 0); \
      }                                                                         \
    }                                                                           \
  } while (0)

  LOADT(0);
  WRITET(0);
  __syncthreads();

  for (int T = 0; T < nt; ++T) {
    if (T + 1 < nt) LOADT(T + 1);       // loads issue before compute; waitcnt at WRITET
    COMPUTE(T & 1);
    if (T + 1 < nt) WRITET((T + 1) & 1);
    __syncthreads();
  }
#undef LOADT
#undef WRITET
#undef COMPUTE

#pragma unroll
  for (int mi = 0; mi < 4; ++mi) {
#pragma unroll
    for (int n = 0; n < 4; ++n) {
      int col = tileN + wn + n * 16 + lr16;
      float bv = bias[col];
#pragma unroll
      for (int qi = 0; qi < 4; ++qi) {
        int row = tileM + wm + mi * 16 + kc4 * 4 + qi;
        if (row < M) {
          float v = acc[mi][n][qi] + bv;
          if (GELU) v = gelu_f(v);
          size_t o = (size_t)row * N + col;
          if (NRES >= 1) v += RES1B ? b2f(res1b[o]) : res1[o];
          if (NRES >= 2) v += res2[o];
          if (WF32) outF[o] = v;
          if (WBF16) outB[o] = f2b(v);
        }
      }
    }
  }
}

// ---------------- V transpose: src[b*TB+tok][src_off+h*64+d] -> dst[bh][d][tok] ----------------
__global__ __launch_bounds__(256) void k_vtrans(const unsigned short* __restrict__ src,
                                                int src_stride, int src_off, int TB,
                                                unsigned short* __restrict__ dst, int dst_tstride) {
  __shared__ unsigned short tile[64][72];
  int tb = blockIdx.x, bh = blockIdx.y;
  int b = bh >> 4, h = bh & 15;
  int t = threadIdx.x;
  int r = t >> 2, c0 = (t & 3) * 16;
  int tok = tb * 64 + r; if (tok >= TB) tok = TB - 1;
  const unsigned short* s = src + (size_t)(b * TB + tok) * src_stride + src_off + h * 64 + c0;
  *(ushort8v*)&tile[r][c0] = *(const ushort8v*)s;
  *(ushort8v*)&tile[r][c0 + 8] = *(const ushort8v*)(s + 8);
  __syncthreads();
  unsigned short tmp[16];
#pragma unroll
  for (int j = 0; j < 16; ++j) tmp[j] = tile[c0 + j][r];
  unsigned short* dp = dst + ((size_t)bh * 64 + r) * dst_tstride + tb * 64 + c0;
  *(ushort8v*)dp = *(const ushort8v*)&tmp[0];
  *(ushort8v*)(dp + 8) = *(const ushort8v*)&tmp[8];
}

// ---------------- MFMA flash attention ----------------
template <bool CAUSAL>
__global__ __launch_bounds__(256) void k_attn(
    const unsigned short* __restrict__ Qb, int q_stride,
    const unsigned short* __restrict__ Kb, int k_stride, int k_off, int TKR,
    const unsigned short* __restrict__ Vt, int vt_tstride,
    unsigned short* __restrict__ out, int Tk) {
  __shared__ unsigned short Kl[64 * 72];
  __shared__ unsigned short Vl[64 * 72];
  __shared__ unsigned short Pl[4][16 * 72];
  const int swz = xcd_swz(blockIdx.x, gridDim.x);
  int qb = swz & 15, bh = swz >> 4;
  int b = bh >> 4, h = bh & 15;
  int t = threadIdx.x, lane = t & 63, w = t >> 6;
  int g = lane >> 4, lc = lane & 15;

  int qrow_g = qb * 64 + w * 16 + lc;
  const unsigned short* qp = Qb + (size_t)(b * 1024 + qrow_g) * q_stride + h * 64 + g * 8;
  short8v aq0 = *(const short8v*)qp;
  short8v aq1 = *(const short8v*)(qp + 32);

  f32x4 o[4];
  float m_[4], l_[4];
#pragma unroll
  for (int dt = 0; dt < 4; ++dt) o[dt] = f32x4{0.f, 0.f, 0.f, 0.f};
#pragma unroll
  for (int r = 0; r < 4; ++r) { m_[r] = -3.0e38f; l_[r] = 0.0f; }

  int srow = t >> 2;
  int sc = (t & 3) * 16;
  int ntiles = CAUSAL ? (qb + 1) : ((Tk + 63) >> 6);

  for (int kt = 0; kt < ntiles; ++kt) {
    __syncthreads();
    {
      int kg = kt * 64 + srow;
      if (!CAUSAL && kg >= Tk) kg = Tk - 1;
      const unsigned short* ks = Kb + (size_t)(b * TKR + kg) * k_stride + k_off + h * 64 + sc;
      *(ushort8v*)&Kl[srow * 72 + sc]     = *(const ushort8v*)ks;
      *(ushort8v*)&Kl[srow * 72 + sc + 8] = *(const ushort8v*)(ks + 8);
      const unsigned short* vs = Vt + ((size_t)bh * 64 + srow) * vt_tstride + kt * 64 + sc;
      *(ushort8v*)&Vl[srow * 72 + sc]     = *(const ushort8v*)vs;
      *(ushort8v*)&Vl[srow * 72 + sc + 8] = *(const ushort8v*)(vs + 8);
    }
    __syncthreads();

    f32x4 s[4];
#pragma unroll
    for (int jt = 0; jt < 4; ++jt) {
      short8v bk0 = *(const short8v*)&Kl[(jt * 16 + lc) * 72 + g * 8];
      short8v bk1 = *(const short8v*)&Kl[(jt * 16 + lc) * 72 + g * 8 + 32];
      f32x4 acc = f32x4{0.f, 0.f, 0.f, 0.f};
      acc = __builtin_amdgcn_mfma_f32_16x16x32_bf16(aq0, bk0, acc, 0, 0, 0);
      acc = __builtin_amdgcn_mfma_f32_16x16x32_bf16(aq1, bk1, acc, 0, 0, 0);
      s[jt] = acc;
    }
#pragma unroll
    for (int jt = 0; jt < 4; ++jt)
#pragma unroll
      for (int r = 0; r < 4; ++r) {
        float sv = s[jt][r] * 0.125f;
        bool masked = CAUSAL ? (kt == qb && (jt * 16 + lc) > (w * 16 + g * 4 + r))
                             : (kt * 64 + jt * 16 + lc >= Tk);
        s[jt][r] = masked ? -3.0e38f : sv;
      }
    float f[4];
#pragma unroll
    for (int r = 0; r < 4; ++r) {
      float mx = fmaxf(fmaxf(s[0][r], s[1][r]), fmaxf(s[2][r], s[3][r]));
      mx = fmaxf(mx, __shfl_xor(mx, 1));
      mx = fmaxf(mx, __shfl_xor(mx, 2));
      mx = fmaxf(mx, __shfl_xor(mx, 4));
      mx = fmaxf(mx, __shfl_xor(mx, 8));
      float mnew = fmaxf(m_[r], mx);
      f[r] = __expf(m_[r] - mnew);
      m_[r] = mnew;
      float rsum = 0.0f;
#pragma unroll
      for (int jt = 0; jt < 4; ++jt) {
        float p = __expf(s[jt][r] - mnew);
        s[jt][r] = p;
        rsum += p;
      }
      rsum += __shfl_xor(rsum, 1);
      rsum += __shfl_xor(rsum, 2);
      rsum += __shfl_xor(rsum, 4);
      rsum += __shfl_xor(rsum, 8);
      l_[r] = l_[r] * f[r] + rsum;
    }
#pragma unroll
    for (int dt = 0; dt < 4; ++dt)
#pragma unroll
      for (int r = 0; r < 4; ++r) o[dt][r] *= f[r];
#pragma unroll
    for (int jt = 0; jt < 4; ++jt)
#pragma unroll
      for (int r = 0; r < 4; ++r)
        Pl[w][(g * 4 + r) * 72 + jt * 16 + lc] = f2b(s[jt][r]);
    short8v ap0 = *(const short8v*)&Pl[w][lc * 72 + g * 8];
    short8v ap1 = *(const short8v*)&Pl[w][lc * 72 + g * 8 + 32];
#pragma unroll
    for (int dt = 0; dt < 4; ++dt) {
      short8v bv0 = *(const short8v*)&Vl[(dt * 16 + lc) * 72 + g * 8];
      short8v bv1 = *(const short8v*)&Vl[(dt * 16 + lc) * 72 + g * 8 + 32];
      o[dt] = __builtin_amdgcn_mfma_f32_16x16x32_bf16(ap0, bv0, o[dt], 0, 0, 0);
      o[dt] = __builtin_amdgcn_mfma_f32_16x16x32_bf16(ap1, bv1, o[dt], 0, 0, 0);
    }
  }
  size_t orow = (size_t)(b * 1024 + qb * 64 + w * 16) * 1024 + h * 64;
#pragma unroll
  for (int r = 0; r < 4; ++r) {
    float inv = 1.0f / l_[r];
#pragma unroll
    for (int dt = 0; dt < 4; ++dt)
      out[orow + (size_t)(g * 4 + r) * 1024 + dt * 16 + lc] = f2b(o[dt][r] * inv);
  }
}

extern "C" void kernel_launch(void* const* d_in, const int* in_sizes, int n_in,
                              void* d_out, int out_size, void* d_ws, size_t ws_size,
                              hipStream_t stream) {
  (void)in_sizes; (void)n_in; (void)out_size; (void)ws_size;
  const float* x       = (const float*)d_in[0];
  const float* enc     = (const float*)d_in[1];
  const float* ln1_g   = (const float*)d_in[3];
  const float* ln1_b   = (const float*)d_in[4];
  const float* ln2_g   = (const float*)d_in[5];
  const float* ln2_b   = (const float*)d_in[6];
  const float* ln3_g   = (const float*)d_in[7];
  const float* ln3_b   = (const float*)d_in[8];
  const float* attn_w  = (const float*)d_in[9];
  const float* attn_b  = (const float*)d_in[10];
  const float* aproj_w = (const float*)d_in[11];
  const float* aproj_b = (const float*)d_in[12];
  const float* ca_w    = (const float*)d_in[13];
  const float* ca_b    = (const float*)d_in[14];
  const float* caproj_w= (const float*)d_in[15];
  const float* caproj_b= (const float*)d_in[16];
  const float* fc_w    = (const float*)d_in[17];
  const float* fc_b    = (const float*)d_in[18];
  const float* mproj_w = (const float*)d_in[19];
  const float* mproj_b = (const float*)d_in[20];
  const float* down_w  = (const float*)d_in[21];
  const float* down_b  = (const float*)d_in[22];
  const float* up_w    = (const float*)d_in[23];
  const float* up_b    = (const float*)d_in[24];
  float* out = (float*)d_out;
  char* ws = (char*)d_ws;

  const size_t O_ENC = 34603008, O_LN = 36708352, O_BIG = 45096960,
               O_XRES = 78651392, O_ATTN = 112205824;

  unsigned short* encbf     = (unsigned short*)(ws + O_ENC);
  unsigned short* lnout     = (unsigned short*)(ws + O_LN);
  unsigned short* hbf       = (unsigned short*)(ws + O_LN);            // after fc consumed
  unsigned short* qkvb      = (unsigned short*)(ws + O_BIG);
  unsigned short* vt_self   = (unsigned short*)(ws + O_BIG + 25165824); // alive with qkvb
  unsigned short* q2b       = (unsigned short*)(ws + O_BIG);           // after self path done
  unsigned short* kvb       = (unsigned short*)(ws + O_BIG + 8388608);
  unsigned short* vt_cross  = (unsigned short*)(ws + O_BIG + 12599296);
  unsigned short* caout     = (unsigned short*)(ws + O_BIG + 15220736);
  unsigned short* fcout     = (unsigned short*)(ws + O_BIG);           // after cross path done
  float*          xres      = (float*)(ws + O_XRES);
  unsigned short* attnout   = (unsigned short*)(ws + O_ATTN);
  unsigned short* dmid      = (unsigned short*)(ws + O_ATTN);          // after aproj consumed

  dim3 blk(256);

  // 1. enc -> bf16 (weight transposes eliminated: GEMMs read f32 weights directly)
  k_enccvt<<<dim3(1028), blk, 0, stream>>>(enc, encbf);

  // 3. ln1(x) ; qkv ; V-transpose ; self-attn ; aproj + residual(x) -> xres
  k_ln<<<dim3(4096), blk, 0, stream>>>(x, ln1_g, ln1_b, lnout);
  k_gf<false, false, true, 0, false><<<dim3(768), blk, 0, stream>>>(
      lnout, 1024, attn_w, 3072, attn_b, nullptr, nullptr, nullptr, nullptr, qkvb,
      4096, 3072, 1024, 24);
  k_vtrans<<<dim3(16, 64), blk, 0, stream>>>(qkvb, 3072, 2048, 1024, vt_self, 1024);
  k_attn<true><<<dim3(1024), blk, 0, stream>>>(
      qkvb, 3072, qkvb, 3072, 1024, 1024, vt_self, 1024, attnout, 1024);
  k_gf<false, true, false, 1, false><<<dim3(256), blk, 0, stream>>>(
      attnout, 1024, aproj_w, 1024, aproj_b, x, nullptr, nullptr, xres, nullptr,
      4096, 1024, 1024, 8);

  // 4. ln2(xres) ; q2 ; kv(enc) ; V-transpose ; cross-attn ; caproj + residual -> xres
  k_ln<<<dim3(4096), blk, 0, stream>>>(xres, ln2_g, ln2_b, lnout);
  k_gf<false, false, true, 0, false><<<dim3(256), blk, 0, stream>>>(
      lnout, 1024, ca_w, 3072, ca_b, nullptr, nullptr, nullptr, nullptr, q2b,
      4096, 1024, 1024, 8);
  k_gf<false, false, true, 0, false><<<dim3(144), blk, 0, stream>>>(
      encbf, 1024, ca_w + 1024, 3072, ca_b + 1024, nullptr, nullptr,
      nullptr, nullptr, kvb, 1028, 2048, 1024, 16);
  k_vtrans<<<dim3(5, 64), blk, 0, stream>>>(kvb, 2048, 1024, 257, vt_cross, 320);
  k_attn<false><<<dim3(1024), blk, 0, stream>>>(
      q2b, 1024, kvb, 2048, 0, 257, vt_cross, 320, caout, 257);
  k_gf<false, true, false, 1, false><<<dim3(256), blk, 0, stream>>>(
      caout, 1024, caproj_w, 1024, caproj_b, xres, nullptr, nullptr, xres, nullptr,
      4096, 1024, 1024, 8);

  // 5. ln3(xres) ; fc+gelu ; mproj -> hbf
  k_ln<<<dim3(4096), blk, 0, stream>>>(xres, ln3_g, ln3_b, lnout);
  k_gf<true, false, true, 0, false><<<dim3(1024), blk, 0, stream>>>(
      lnout, 1024, fc_w, 4096, fc_b, nullptr, nullptr, nullptr, nullptr, fcout,
      4096, 4096, 1024, 32);
  k_gf<false, false, true, 0, false><<<dim3(256), blk, 0, stream>>>(
      fcout, 4096, mproj_w, 1024, mproj_b, nullptr, nullptr, nullptr, nullptr, hbf,
      4096, 1024, 4096, 8);

  // 6. adapter: down+gelu ; up + up_b + h(bf16) + xres -> out
  k_gf<true, false, true, 0, false><<<dim3(64), blk, 0, stream>>>(
      hbf, 1024, down_w, 256, down_b, nullptr, nullptr, nullptr, nullptr, dmid,
      4096, 256, 1024, 2);
  k_gf<false, true, false, 2, true><<<dim3(256), blk, 0, stream>>>(
      dmid, 256, up_w, 1024, up_b, nullptr, hbf, xres, out, nullptr,
      4096, 1024, 256, 8);
}

// Round 17
// 452.592 us; speedup vs baseline: 1.1540x; 1.1540x over previous
//
#include <hip/hip_runtime.h>

typedef __attribute__((ext_vector_type(8))) short short8v;
typedef __attribute__((ext_vector_type(8))) unsigned short ushort8v;
typedef __attribute__((ext_vector_type(4))) unsigned short ushort4v;
typedef __attribute__((ext_vector_type(4))) float f32x4;

__device__ __forceinline__ unsigned short f2b(float f) {
  unsigned int u = __float_as_uint(f);
  unsigned int r = (u + 0x7FFFu + ((u >> 16) & 1u)) >> 16;
  return (unsigned short)r;
}
__device__ __forceinline__ float b2f(unsigned short h) {
  return __uint_as_float(((unsigned int)h) << 16);
}
__device__ __forceinline__ float gelu_f(float x) {
  float z = 0.7978845608028654f * (x + 0.044715f * x * x * x);
  float e = __expf(2.0f * z);
  float t = 1.0f - 2.0f / (e + 1.0f);
  return 0.5f * x * (1.0f + t);
}
// bijective XCD swizzle (m204)
__device__ __forceinline__ int xcd_swz(int wgid, int nwg) {
  int q = nwg >> 3, r = nwg & 7;
  int xcd = wgid & 7, idx = wgid >> 3;
  return (xcd < r ? xcd * (q + 1) : r * (q + 1) + (xcd - r) * q) + idx;
}
// 2D XCD region mapping (fc FETCH 69.9->41.2 MB measured)
__device__ __forceinline__ void map_tile(int wgid, int nwg, int nbx, int& tm, int& tn) {
  int nby = nwg / nbx;
  if ((nwg & 7) == 0 && (nby & 3) == 0 && (nbx & 1) == 0) {
    int x = wgid & 7, idx = wgid >> 3;
    int rh = nby >> 2, rw = nbx >> 1;
    int xr = x >> 1, xc = x & 1;
    tm = xr * rh + idx / rw;
    tn = xc * rw + idx % rw;
  } else {
    int swz = xcd_swz(wgid, nwg);
    tm = swz / nbx;
    tn = swz % nbx;
  }
}

// ---------------- merged weight prep: 8 transposes (f32 [K][N] -> bf16 [N][K]) + enc cvt ----
__global__ __launch_bounds__(256) void k_wprep(
    const float* aw, unsigned short* awt,
    const float* apw, unsigned short* apwt,
    const float* cw, unsigned short* cwt,
    const float* cpw, unsigned short* cpwt,
    const float* fw, unsigned short* fwt,
    const float* mw, unsigned short* mwt,
    const float* dw, unsigned short* dwt,
    const float* uw, unsigned short* uwt,
    const float* enc, unsigned short* encb) {
  __shared__ float tile[64][65];
  int bid = blockIdx.x, t = threadIdx.x;
  const float* w; unsigned short* wt; int K, N, gx, l;
  if      (bid < 768)  { w = aw;  wt = awt;  K = 1024; N = 3072; gx = 48; l = bid; }
  else if (bid < 1024) { w = apw; wt = apwt; K = 1024; N = 1024; gx = 16; l = bid - 768; }
  else if (bid < 1792) { w = cw;  wt = cwt;  K = 1024; N = 3072; gx = 48; l = bid - 1024; }
  else if (bid < 2048) { w = cpw; wt = cpwt; K = 1024; N = 1024; gx = 16; l = bid - 1792; }
  else if (bid < 3072) { w = fw;  wt = fwt;  K = 1024; N = 4096; gx = 64; l = bid - 2048; }
  else if (bid < 4096) { w = mw;  wt = mwt;  K = 4096; N = 1024; gx = 16; l = bid - 3072; }
  else if (bid < 4160) { w = dw;  wt = dwt;  K = 1024; N = 256;  gx = 4;  l = bid - 4096; }
  else if (bid < 4224) { w = uw;  wt = uwt;  K = 256;  N = 1024; gx = 16; l = bid - 4160; }
  else {
    size_t i = ((size_t)(bid - 4224) * 256 + t) * 4;
    f32x4 v = *(const f32x4*)&enc[i];
    ushort4v o;
#pragma unroll
    for (int j = 0; j < 4; ++j) o[j] = f2b(v[j]);
    *(ushort4v*)&encb[i] = o;
    return;
  }
  int bx = l % gx, by = l / gx;
  int tn = bx * 64, tk = by * 64;
  int c = t & 63, r0 = t >> 6;
#pragma unroll
  for (int p = 0; p < 16; ++p) {
    int r = r0 + p * 4;
    tile[r][c] = w[(size_t)(tk + r) * N + tn + c];
  }
  __syncthreads();
#pragma unroll
  for (int p = 0; p < 16; ++p) {
    int r = r0 + p * 4;
    wt[(size_t)(tn + r) * K + tk + c] = f2b(tile[c][r]);
  }
}

// ---------------- LayerNorm over C=1024, out bf16 ----------------
__global__ __launch_bounds__(256) void k_ln(const float* __restrict__ in,
                                            const float* __restrict__ g,
                                            const float* __restrict__ b,
                                            unsigned short* __restrict__ out) {
  int row = blockIdx.x;
  const float* x = in + (size_t)row * 1024;
  int t = threadIdx.x;
  float v0 = x[t], v1 = x[t + 256], v2 = x[t + 512], v3 = x[t + 768];
  float s = v0 + v1 + v2 + v3;
  float s2 = v0 * v0 + v1 * v1 + v2 * v2 + v3 * v3;
#pragma unroll
  for (int m = 1; m < 64; m <<= 1) { s += __shfl_xor(s, m); s2 += __shfl_xor(s2, m); }
  __shared__ float rs[4], rs2[4];
  int w = t >> 6;
  if ((t & 63) == 0) { rs[w] = s; rs2[w] = s2; }
  __syncthreads();
  s = rs[0] + rs[1] + rs[2] + rs[3];
  s2 = rs2[0] + rs2[1] + rs2[2] + rs2[3];
  float mean = s * (1.0f / 1024.0f);
  float var = s2 * (1.0f / 1024.0f) - mean * mean;
  float rinv = rsqrtf(var + 1e-5f);
  unsigned short* o = out + (size_t)row * 1024;
  o[t]       = f2b((v0 - mean) * rinv * g[t]       + b[t]);
  o[t + 256] = f2b((v1 - mean) * rinv * g[t + 256] + b[t + 256]);
  o[t + 512] = f2b((v2 - mean) * rinv * g[t + 512] + b[t + 512]);
  o[t + 768] = f2b((v3 - mean) * rinv * g[t + 768] + b[t + 768]);
}

// ---------------- 128x128 GEMM: single 32KB LDS + reg prefetch dist 2 (R13, best) ----------
// Optional split-K (only used for `down`): blockIdx = split*nsub+sub, f32 partials to outF.
template <bool GELU, bool BIAS, bool WF32, bool WBF16, int NRES, bool RES1B>
__global__ __launch_bounds__(256, 2) void k_g128r(
    const unsigned short* __restrict__ A, int lda,
    const unsigned short* __restrict__ W, int ldw,
    const float* __restrict__ bias,
    const float* __restrict__ res1, const unsigned short* __restrict__ res1b,
    const float* __restrict__ res2,
    float* __restrict__ outF, unsigned short* __restrict__ outB,
    int M, int N, int K, int nbx, int splitk, size_t zO) {
  __shared__ unsigned short lds[16384];   // A[128][64] + B[128][64], one buffer (32KB)
  const int t = threadIdx.x;
  const int nsub = gridDim.x / splitk;
  const int split = blockIdx.x / nsub;
  const int sub = blockIdx.x % nsub;
  int tm, tn;
  map_tile(sub, nsub, nbx, tm, tn);
  const int tileM = tm * 128, tileN = tn * 128;
  const int Keff = K / splitk;
  const int lane = t & 63, w = t >> 6;
  const int wm = (w >> 1) * 64, wn = (w & 1) * 64;
  const int lr16 = lane & 15, kc4 = lane >> 4;

  const int sr = t >> 1, hb = t & 1;
  int gr = tileM + sr; if (gr >= M) gr = M - 1;
  const unsigned short* ga = A + (size_t)gr * lda + (size_t)split * Keff + hb * 32;
  const unsigned short* gw = W + (size_t)(tileN + sr) * ldw + (size_t)split * Keff + hb * 32;
  unsigned short* const wbA = &lds[sr * 64];
  const int wsl[4] = {((hb * 4 + 0) ^ (sr & 7)) * 8, ((hb * 4 + 1) ^ (sr & 7)) * 8,
                      ((hb * 4 + 2) ^ (sr & 7)) * 8, ((hb * 4 + 3) ^ (sr & 7)) * 8};

  f32x4 acc[4][4];
#pragma unroll
  for (int i = 0; i < 4; ++i)
#pragma unroll
    for (int j = 0; j < 4; ++j) acc[i][j] = f32x4{0.f, 0.f, 0.f, 0.f};

  const int nt = Keff >> 6;   // even for all ops here
  ushort8v raE[4], rbE[4], raO[4], rbO[4];

#define LOADT(T, ra, rb)                                      \
  do {                                                        \
    int ko = (T) << 6;                                        \
    _Pragma("unroll") for (int j = 0; j < 4; ++j) {           \
      ra[j] = *(const ushort8v*)(ga + ko + j * 8);            \
      rb[j] = *(const ushort8v*)(gw + ko + j * 8);            \
    }                                                         \
  } while (0)
#define WRITET(ra, rb)                                        \
  do {                                                        \
    _Pragma("unroll") for (int j = 0; j < 4; ++j) {           \
      *(ushort8v*)(wbA + wsl[j]) = ra[j];                     \
      *(ushort8v*)(wbA + 8192 + wsl[j]) = rb[j];              \
    }                                                         \
  } while (0)
#define COMPUTE()                                                               \
  do {                                                                          \
    _Pragma("unroll") for (int ks = 0; ks < 2; ++ks) {                          \
      short8v bfr[4];                                                           \
      _Pragma("unroll") for (int n = 0; n < 4; ++n) {                           \
        int r = wn + n * 16 + lr16;                                             \
        int sl = ((ks * 4 + kc4) ^ (r & 7)) * 8;                                \
        bfr[n] = *(const short8v*)&lds[8192 + r * 64 + sl];                     \
      }                                                                         \
      _Pragma("unroll") for (int mi = 0; mi < 4; ++mi) {                        \
        int r = wm + mi * 16 + lr16;                                            \
        int sl = ((ks * 4 + kc4) ^ (r & 7)) * 8;                                \
        short8v af = *(const short8v*)&lds[r * 64 + sl];                        \
        _Pragma("unroll") for (int n = 0; n < 4; ++n)                           \
          acc[mi][n] =                                                          \
              __builtin_amdgcn_mfma_f32_16x16x32_bf16(af, bfr[n], acc[mi][n], 0, 0, 0); \
      }                                                                         \
    }                                                                           \
  } while (0)

  LOADT(0, raE, rbE);
  WRITET(raE, rbE);
  if (nt > 1) LOADT(1, raO, rbO);
  __syncthreads();

  for (int T = 0; T < nt; T += 2) {
    if (T + 2 < nt) LOADT(T + 2, raE, rbE);
    COMPUTE();                        // tile T
    __syncthreads();                  // done reading tile T
    if (T + 1 < nt) {
      WRITET(raO, rbO);               // tile T+1 -> LDS
      if (T + 3 < nt) LOADT(T + 3, raO, rbO);
      __syncthreads();                // tile T+1 visible
      COMPUTE();                      // tile T+1
      __syncthreads();
      if (T + 2 < nt) WRITET(raE, rbE);
      __syncthreads();
    }
  }
#undef LOADT
#undef WRITET
#undef COMPUTE

  if (WF32 && splitk > 1) outF += (size_t)split * zO;
#pragma unroll
  for (int mi = 0; mi < 4; ++mi) {
#pragma unroll
    for (int n = 0; n < 4; ++n) {
      int col = tileN + wn + n * 16 + lr16;
      float bv = BIAS ? bias[col] : 0.0f;
#pragma unroll
      for (int qi = 0; qi < 4; ++qi) {
        int row = tileM + wm + mi * 16 + kc4 * 4 + qi;
        if (row < M) {
          float v = acc[mi][n][qi] + bv;
          if (GELU) v = gelu_f(v);
          size_t o = (size_t)row * N + col;
          if (NRES >= 1) v += RES1B ? b2f(res1b[o]) : res1[o];
          if (NRES >= 2) v += res2[o];
          if (WF32) outF[o] = v;
          if (WBF16) outB[o] = f2b(v);
        }
      }
    }
  }
}

// ---------------- split-K reduce: out_bf16 = gelu(sum_{s<4} p[s] + bias) ----------------
template <bool GELU, int NM1>
__global__ __launch_bounds__(256) void k_red(const float* __restrict__ p,
                                             const float* __restrict__ bias,
                                             unsigned short* __restrict__ ob, size_t S) {
  size_t i = ((size_t)blockIdx.x * 256 + threadIdx.x) * 4;
  f32x4 v = *(const f32x4*)&p[i];
  v += *(const f32x4*)&p[i + S];
  v += *(const f32x4*)&p[i + 2 * S];
  v += *(const f32x4*)&p[i + 3 * S];
  v += *(const f32x4*)&bias[i & NM1];
  ushort4v o;
#pragma unroll
  for (int j = 0; j < 4; ++j) o[j] = f2b(GELU ? gelu_f(v[j]) : v[j]);
  *(ushort4v*)&ob[i] = o;
}

// ---------------- V transpose: src[b*TB+tok][src_off+h*64+d] -> dst[bh][d][tok] ----------------
__global__ __launch_bounds__(256) void k_vtrans(const unsigned short* __restrict__ src,
                                                int src_stride, int src_off, int TB,
                                                unsigned short* __restrict__ dst, int dst_tstride) {
  __shared__ unsigned short tile[64][72];
  int tb = blockIdx.x, bh = blockIdx.y;
  int b = bh >> 4, h = bh & 15;
  int t = threadIdx.x;
  int r = t >> 2, c0 = (t & 3) * 16;
  int tok = tb * 64 + r; if (tok >= TB) tok = TB - 1;
  const unsigned short* s = src + (size_t)(b * TB + tok) * src_stride + src_off + h * 64 + c0;
  *(ushort8v*)&tile[r][c0] = *(const ushort8v*)s;
  *(ushort8v*)&tile[r][c0 + 8] = *(const ushort8v*)(s + 8);
  __syncthreads();
  unsigned short tmp[16];
#pragma unroll
  for (int j = 0; j < 16; ++j) tmp[j] = tile[c0 + j][r];
  unsigned short* dp = dst + ((size_t)bh * 64 + r) * dst_tstride + tb * 64 + c0;
  *(ushort8v*)dp = *(const ushort8v*)&tmp[0];
  *(ushort8v*)(dp + 8) = *(const ushort8v*)&tmp[8];
}

// ---------------- MFMA flash attention ----------------
template <bool CAUSAL>
__global__ __launch_bounds__(256) void k_attn(
    const unsigned short* __restrict__ Qb, int q_stride,
    const unsigned short* __restrict__ Kb, int k_stride, int k_off, int TKR,
    const unsigned short* __restrict__ Vt, int vt_tstride,
    unsigned short* __restrict__ out, int Tk) {
  __shared__ unsigned short Kl[64 * 72];
  __shared__ unsigned short Vl[64 * 72];
  __shared__ unsigned short Pl[4][16 * 72];
  const int swz = xcd_swz(blockIdx.x, gridDim.x);
  int qb = swz & 15, bh = swz >> 4;
  int b = bh >> 4, h = bh & 15;
  int t = threadIdx.x, lane = t & 63, w = t >> 6;
  int g = lane >> 4, lc = lane & 15;

  int qrow_g = qb * 64 + w * 16 + lc;
  const unsigned short* qp = Qb + (size_t)(b * 1024 + qrow_g) * q_stride + h * 64 + g * 8;
  short8v aq0 = *(const short8v*)qp;
  short8v aq1 = *(const short8v*)(qp + 32);

  f32x4 o[4];
  float m_[4], l_[4];
#pragma unroll
  for (int dt = 0; dt < 4; ++dt) o[dt] = f32x4{0.f, 0.f, 0.f, 0.f};
#pragma unroll
  for (int r = 0; r < 4; ++r) { m_[r] = -3.0e38f; l_[r] = 0.0f; }

  int srow = t >> 2;
  int sc = (t & 3) * 16;
  int ntiles = CAUSAL ? (qb + 1) : ((Tk + 63) >> 6);

  for (int kt = 0; kt < ntiles; ++kt) {
    __syncthreads();
    {
      int kg = kt * 64 + srow;
      if (!CAUSAL && kg >= Tk) kg = Tk - 1;
      const unsigned short* ks = Kb + (size_t)(b * TKR + kg) * k_stride + k_off + h * 64 + sc;
      *(ushort8v*)&Kl[srow * 72 + sc]     = *(const ushort8v*)ks;
      *(ushort8v*)&Kl[srow * 72 + sc + 8] = *(const ushort8v*)(ks + 8);
      const unsigned short* vs = Vt + ((size_t)bh * 64 + srow) * vt_tstride + kt * 64 + sc;
      *(ushort8v*)&Vl[srow * 72 + sc]     = *(const ushort8v*)vs;
      *(ushort8v*)&Vl[srow * 72 + sc + 8] = *(const ushort8v*)(vs + 8);
    }
    __syncthreads();

    f32x4 s[4];
#pragma unroll
    for (int jt = 0; jt < 4; ++jt) {
      short8v bk0 = *(const short8v*)&Kl[(jt * 16 + lc) * 72 + g * 8];
      short8v bk1 = *(const short8v*)&Kl[(jt * 16 + lc) * 72 + g * 8 + 32];
      f32x4 acc = f32x4{0.f, 0.f, 0.f, 0.f};
      acc = __builtin_amdgcn_mfma_f32_16x16x32_bf16(aq0, bk0, acc, 0, 0, 0);
      acc = __builtin_amdgcn_mfma_f32_16x16x32_bf16(aq1, bk1, acc, 0, 0, 0);
      s[jt] = acc;
    }
#pragma unroll
    for (int jt = 0; jt < 4; ++jt)
#pragma unroll
      for (int r = 0; r < 4; ++r) {
        float sv = s[jt][r] * 0.125f;
        bool masked = CAUSAL ? (kt == qb && (jt * 16 + lc) > (w * 16 + g * 4 + r))
                             : (kt * 64 + jt * 16 + lc >= Tk);
        s[jt][r] = masked ? -3.0e38f : sv;
      }
    float f[4];
#pragma unroll
    for (int r = 0; r < 4; ++r) {
      float mx = fmaxf(fmaxf(s[0][r], s[1][r]), fmaxf(s[2][r], s[3][r]));
      mx = fmaxf(mx, __shfl_xor(mx, 1));
      mx = fmaxf(mx, __shfl_xor(mx, 2));
      mx = fmaxf(mx, __shfl_xor(mx, 4));
      mx = fmaxf(mx, __shfl_xor(mx, 8));
      float mnew = fmaxf(m_[r], mx);
      f[r] = __expf(m_[r] - mnew);
      m_[r] = mnew;
      float rsum = 0.0f;
#pragma unroll
      for (int jt = 0; jt < 4; ++jt) {
        float p = __expf(s[jt][r] - mnew);
        s[jt][r] = p;
        rsum += p;
      }
      rsum += __shfl_xor(rsum, 1);
      rsum += __shfl_xor(rsum, 2);
      rsum += __shfl_xor(rsum, 4);
      rsum += __shfl_xor(rsum, 8);
      l_[r] = l_[r] * f[r] + rsum;
    }
#pragma unroll
    for (int dt = 0; dt < 4; ++dt)
#pragma unroll
      for (int r = 0; r < 4; ++r) o[dt][r] *= f[r];
#pragma unroll
    for (int jt = 0; jt < 4; ++jt)
#pragma unroll
      for (int r = 0; r < 4; ++r)
        Pl[w][(g * 4 + r) * 72 + jt * 16 + lc] = f2b(s[jt][r]);
    short8v ap0 = *(const short8v*)&Pl[w][lc * 72 + g * 8];
    short8v ap1 = *(const short8v*)&Pl[w][lc * 72 + g * 8 + 32];
#pragma unroll
    for (int dt = 0; dt < 4; ++dt) {
      short8v bv0 = *(const short8v*)&Vl[(dt * 16 + lc) * 72 + g * 8];
      short8v bv1 = *(const short8v*)&Vl[(dt * 16 + lc) * 72 + g * 8 + 32];
      o[dt] = __builtin_amdgcn_mfma_f32_16x16x32_bf16(ap0, bv0, o[dt], 0, 0, 0);
      o[dt] = __builtin_amdgcn_mfma_f32_16x16x32_bf16(ap1, bv1, o[dt], 0, 0, 0);
    }
  }
  size_t orow = (size_t)(b * 1024 + qb * 64 + w * 16) * 1024 + h * 64;
#pragma unroll
  for (int r = 0; r < 4; ++r) {
    float inv = 1.0f / l_[r];
#pragma unroll
    for (int dt = 0; dt < 4; ++dt)
      out[orow + (size_t)(g * 4 + r) * 1024 + dt * 16 + lc] = f2b(o[dt][r] * inv);
  }
}

extern "C" void kernel_launch(void* const* d_in, const int* in_sizes, int n_in,
                              void* d_out, int out_size, void* d_ws, size_t ws_size,
                              hipStream_t stream) {
  (void)in_sizes; (void)n_in; (void)out_size;
  const float* x       = (const float*)d_in[0];
  const float* enc     = (const float*)d_in[1];
  const float* ln1_g   = (const float*)d_in[3];
  const float* ln1_b   = (const float*)d_in[4];
  const float* ln2_g   = (const float*)d_in[5];
  const float* ln2_b   = (const float*)d_in[6];
  const float* ln3_g   = (const float*)d_in[7];
  const float* ln3_b   = (const float*)d_in[8];
  const float* attn_w  = (const float*)d_in[9];
  const float* attn_b  = (const float*)d_in[10];
  const float* aproj_w = (const float*)d_in[11];
  const float* aproj_b = (const float*)d_in[12];
  const float* ca_w    = (const float*)d_in[13];
  const float* ca_b    = (const float*)d_in[14];
  const float* caproj_w= (const float*)d_in[15];
  const float* caproj_b= (const float*)d_in[16];
  const float* fc_w    = (const float*)d_in[17];
  const float* fc_b    = (const float*)d_in[18];
  const float* mproj_w = (const float*)d_in[19];
  const float* mproj_b = (const float*)d_in[20];
  const float* down_w  = (const float*)d_in[21];
  const float* down_b  = (const float*)d_in[22];
  const float* up_w    = (const float*)d_in[23];
  const float* up_b    = (const float*)d_in[24];
  float* out = (float*)d_out;
  char* ws = (char*)d_ws;

  const size_t O_WATTN = 0, O_WAPROJ = 6291456, O_WCA = 8388608, O_WCAPROJ = 14680064,
               O_WFC = 16777216, O_WMPROJ = 25165824, O_WDOWN = 33554432, O_WUP = 34078720,
               O_ENC = 34603008, O_LN = 36708352, O_BIG = 45096960,
               O_XRES = 78651392, O_ATTN = 112205824, O_PART = 121634816;

  unsigned short* wt_attn   = (unsigned short*)(ws + O_WATTN);
  unsigned short* wt_aproj  = (unsigned short*)(ws + O_WAPROJ);
  unsigned short* wt_ca     = (unsigned short*)(ws + O_WCA);
  unsigned short* wt_caproj = (unsigned short*)(ws + O_WCAPROJ);
  unsigned short* wt_fc     = (unsigned short*)(ws + O_WFC);
  unsigned short* wt_mproj  = (unsigned short*)(ws + O_WMPROJ);
  unsigned short* wt_down   = (unsigned short*)(ws + O_WDOWN);
  unsigned short* wt_up     = (unsigned short*)(ws + O_WUP);
  unsigned short* encbf     = (unsigned short*)(ws + O_ENC);
  unsigned short* lnout     = (unsigned short*)(ws + O_LN);
  unsigned short* hbf       = (unsigned short*)(ws + O_LN);            // after fc consumed
  unsigned short* qkvb      = (unsigned short*)(ws + O_BIG);
  unsigned short* vt_self   = (unsigned short*)(ws + O_BIG + 25165824); // alive with qkvb
  unsigned short* q2b       = (unsigned short*)(ws + O_BIG);           // after self path done
  unsigned short* kvb       = (unsigned short*)(ws + O_BIG + 8388608);
  unsigned short* vt_cross  = (unsigned short*)(ws + O_BIG + 12599296);
  unsigned short* caout     = (unsigned short*)(ws + O_BIG + 15220736);
  unsigned short* fcout     = (unsigned short*)(ws + O_BIG);           // after cross path done
  float*          xres      = (float*)(ws + O_XRES);
  unsigned short* attnout   = (unsigned short*)(ws + O_ATTN);
  unsigned short* dmid      = (unsigned short*)(ws + O_ATTN);          // after aproj consumed
  float*          part      = (float*)(ws + O_PART);

  bool splitok = ws_size >= O_PART + 4ull * 4096 * 256 * 4;   // 16 MB partials

  dim3 blk(256);

  // 1. merged weight prep (8 transposes + enc cvt)
  k_wprep<<<dim3(5252), blk, 0, stream>>>(
      attn_w, wt_attn, aproj_w, wt_aproj, ca_w, wt_ca, caproj_w, wt_caproj,
      fc_w, wt_fc, mproj_w, wt_mproj, down_w, wt_down, up_w, wt_up, enc, encbf);

  // 3. ln1(x) ; qkv ; V-transpose ; self-attn ; aproj + residual(x) -> xres
  k_ln<<<dim3(4096), blk, 0, stream>>>(x, ln1_g, ln1_b, lnout);
  k_g128r<false, true, false, true, 0, false><<<dim3(768), blk, 0, stream>>>(
      lnout, 1024, wt_attn, 1024, attn_b, nullptr, nullptr, nullptr, nullptr, qkvb,
      4096, 3072, 1024, 24, 1, 0);
  k_vtrans<<<dim3(16, 64), blk, 0, stream>>>(qkvb, 3072, 2048, 1024, vt_self, 1024);
  k_attn<true><<<dim3(1024), blk, 0, stream>>>(
      qkvb, 3072, qkvb, 3072, 1024, 1024, vt_self, 1024, attnout, 1024);
  k_g128r<false, true, true, false, 1, false><<<dim3(256), blk, 0, stream>>>(
      attnout, 1024, wt_aproj, 1024, aproj_b, x, nullptr, nullptr, xres, nullptr,
      4096, 1024, 1024, 8, 1, 0);

  // 4. ln2(xres) ; q2 ; kv(enc) ; V-transpose ; cross-attn ; caproj + residual -> xres
  k_ln<<<dim3(4096), blk, 0, stream>>>(xres, ln2_g, ln2_b, lnout);
  k_g128r<false, true, false, true, 0, false><<<dim3(256), blk, 0, stream>>>(
      lnout, 1024, wt_ca, 1024, ca_b, nullptr, nullptr, nullptr, nullptr, q2b,
      4096, 1024, 1024, 8, 1, 0);
  k_g128r<false, true, false, true, 0, false><<<dim3(144), blk, 0, stream>>>(
      encbf, 1024, wt_ca + (size_t)1024 * 1024, 1024, ca_b + 1024, nullptr, nullptr,
      nullptr, nullptr, kvb, 1028, 2048, 1024, 16, 1, 0);
  k_vtrans<<<dim3(5, 64), blk, 0, stream>>>(kvb, 2048, 1024, 257, vt_cross, 320);
  k_attn<false><<<dim3(1024), blk, 0, stream>>>(
      q2b, 1024, kvb, 2048, 0, 257, vt_cross, 320, caout, 257);
  k_g128r<false, true, true, false, 1, false><<<dim3(256), blk, 0, stream>>>(
      caout, 1024, wt_caproj, 1024, caproj_b, xres, nullptr, nullptr, xres, nullptr,
      4096, 1024, 1024, 8, 1, 0);

  // 5. ln3(xres) ; fc+gelu ; mproj -> hbf
  k_ln<<<dim3(4096), blk, 0, stream>>>(xres, ln3_g, ln3_b, lnout);
  k_g128r<true, true, false, true, 0, false><<<dim3(1024), blk, 0, stream>>>(
      lnout, 1024, wt_fc, 1024, fc_b, nullptr, nullptr, nullptr, nullptr, fcout,
      4096, 4096, 1024, 32, 1, 0);
  k_g128r<false, true, false, true, 0, false><<<dim3(256), blk, 0, stream>>>(
      fcout, 4096, wt_mproj, 4096, mproj_b, nullptr, nullptr, nullptr, nullptr, hbf,
      4096, 1024, 4096, 8, 1, 0);

  // 6. adapter: down+gelu (split-K x4 across full chip) ; up + up_b + h + xres -> out
  if (splitok) {
    k_g128r<false, false, true, false, 0, false><<<dim3(256), blk, 0, stream>>>(
        hbf, 1024, wt_down, 1024, nullptr, nullptr, nullptr, nullptr, part, nullptr,
        4096, 256, 1024, 2, 4, (size_t)4096 * 256);
    k_red<true, 255><<<dim3(1024), blk, 0, stream>>>(part, down_b, dmid,
                                                     (size_t)4096 * 256);
  } else {
    k_g128r<true, true, false, true, 0, false><<<dim3(64), blk, 0, stream>>>(
        hbf, 1024, wt_down, 1024, down_b, nullptr, nullptr, nullptr, nullptr, dmid,
        4096, 256, 1024, 2, 1, 0);
  }
  k_g128r<false, true, true, false, 2, true><<<dim3(256), blk, 0, stream>>>(
      dmid, 256, wt_up, 256, up_b, nullptr, hbf, xres, out, nullptr,
      4096, 1024, 256, 8, 1, 0);
}

// Round 18
// 438.470 us; speedup vs baseline: 1.1912x; 1.0322x over previous
//
#include <hip/hip_runtime.h>

typedef __attribute__((ext_vector_type(8))) short short8v;
typedef __attribute__((ext_vector_type(8))) unsigned short ushort8v;
typedef __attribute__((ext_vector_type(4))) unsigned short ushort4v;
typedef __attribute__((ext_vector_type(4))) float f32x4;

__device__ __forceinline__ unsigned short f2b(float f) {
  unsigned int u = __float_as_uint(f);
  unsigned int r = (u + 0x7FFFu + ((u >> 16) & 1u)) >> 16;
  return (unsigned short)r;
}
__device__ __forceinline__ float b2f(unsigned short h) {
  return __uint_as_float(((unsigned int)h) << 16);
}
__device__ __forceinline__ float gelu_f(float x) {
  float z = 0.7978845608028654f * (x + 0.044715f * x * x * x);
  float e = __expf(2.0f * z);
  float t = 1.0f - 2.0f / (e + 1.0f);
  return 0.5f * x * (1.0f + t);
}
// bijective XCD swizzle (m204)
__device__ __forceinline__ int xcd_swz(int wgid, int nwg) {
  int q = nwg >> 3, r = nwg & 7;
  int xcd = wgid & 7, idx = wgid >> 3;
  return (xcd < r ? xcd * (q + 1) : r * (q + 1) + (xcd - r) * q) + idx;
}
// 2D XCD region mapping (fc FETCH 69.9->41.2 MB measured)
__device__ __forceinline__ void map_tile(int wgid, int nwg, int nbx, int& tm, int& tn) {
  int nby = nwg / nbx;
  if ((nwg & 7) == 0 && (nby & 3) == 0 && (nbx & 1) == 0) {
    int x = wgid & 7, idx = wgid >> 3;
    int rh = nby >> 2, rw = nbx >> 1;
    int xr = x >> 1, xc = x & 1;
    tm = xr * rh + idx / rw;
    tn = xc * rw + idx % rw;
  } else {
    int swz = xcd_swz(wgid, nwg);
    tm = swz / nbx;
    tn = swz % nbx;
  }
}

// ---------------- merged weight prep: 8 transposes (f32 [K][N] -> bf16 [N][K]) + enc cvt ----
__global__ __launch_bounds__(256) void k_wprep(
    const float* aw, unsigned short* awt,
    const float* apw, unsigned short* apwt,
    const float* cw, unsigned short* cwt,
    const float* cpw, unsigned short* cpwt,
    const float* fw, unsigned short* fwt,
    const float* mw, unsigned short* mwt,
    const float* dw, unsigned short* dwt,
    const float* uw, unsigned short* uwt,
    const float* enc, unsigned short* encb) {
  __shared__ float tile[64][65];
  int bid = blockIdx.x, t = threadIdx.x;
  const float* w; unsigned short* wt; int K, N, gx, l;
  if      (bid < 768)  { w = aw;  wt = awt;  K = 1024; N = 3072; gx = 48; l = bid; }
  else if (bid < 1024) { w = apw; wt = apwt; K = 1024; N = 1024; gx = 16; l = bid - 768; }
  else if (bid < 1792) { w = cw;  wt = cwt;  K = 1024; N = 3072; gx = 48; l = bid - 1024; }
  else if (bid < 2048) { w = cpw; wt = cpwt; K = 1024; N = 1024; gx = 16; l = bid - 1792; }
  else if (bid < 3072) { w = fw;  wt = fwt;  K = 1024; N = 4096; gx = 64; l = bid - 2048; }
  else if (bid < 4096) { w = mw;  wt = mwt;  K = 4096; N = 1024; gx = 16; l = bid - 3072; }
  else if (bid < 4160) { w = dw;  wt = dwt;  K = 1024; N = 256;  gx = 4;  l = bid - 4096; }
  else if (bid < 4224) { w = uw;  wt = uwt;  K = 256;  N = 1024; gx = 16; l = bid - 4160; }
  else {
    size_t i = ((size_t)(bid - 4224) * 256 + t) * 4;
    f32x4 v = *(const f32x4*)&enc[i];
    ushort4v o;
#pragma unroll
    for (int j = 0; j < 4; ++j) o[j] = f2b(v[j]);
    *(ushort4v*)&encb[i] = o;
    return;
  }
  int bx = l % gx, by = l / gx;
  int tn = bx * 64, tk = by * 64;
  int c = t & 63, r0 = t >> 6;
#pragma unroll
  for (int p = 0; p < 16; ++p) {
    int r = r0 + p * 4;
    tile[r][c] = w[(size_t)(tk + r) * N + tn + c];
  }
  __syncthreads();
#pragma unroll
  for (int p = 0; p < 16; ++p) {
    int r = r0 + p * 4;
    wt[(size_t)(tn + r) * K + tk + c] = f2b(tile[c][r]);
  }
}

// ---------------- LayerNorm over C=1024, out bf16 ----------------
__global__ __launch_bounds__(256) void k_ln(const float* __restrict__ in,
                                            const float* __restrict__ g,
                                            const float* __restrict__ b,
                                            unsigned short* __restrict__ out) {
  int row = blockIdx.x;
  const float* x = in + (size_t)row * 1024;
  int t = threadIdx.x;
  float v0 = x[t], v1 = x[t + 256], v2 = x[t + 512], v3 = x[t + 768];
  float s = v0 + v1 + v2 + v3;
  float s2 = v0 * v0 + v1 * v1 + v2 * v2 + v3 * v3;
#pragma unroll
  for (int m = 1; m < 64; m <<= 1) { s += __shfl_xor(s, m); s2 += __shfl_xor(s2, m); }
  __shared__ float rs[4], rs2[4];
  int w = t >> 6;
  if ((t & 63) == 0) { rs[w] = s; rs2[w] = s2; }
  __syncthreads();
  s = rs[0] + rs[1] + rs[2] + rs[3];
  s2 = rs2[0] + rs2[1] + rs2[2] + rs2[3];
  float mean = s * (1.0f / 1024.0f);
  float var = s2 * (1.0f / 1024.0f) - mean * mean;
  float rinv = rsqrtf(var + 1e-5f);
  unsigned short* o = out + (size_t)row * 1024;
  o[t]       = f2b((v0 - mean) * rinv * g[t]       + b[t]);
  o[t + 256] = f2b((v1 - mean) * rinv * g[t + 256] + b[t + 256]);
  o[t + 512] = f2b((v2 - mean) * rinv * g[t + 512] + b[t + 512]);
  o[t + 768] = f2b((v3 - mean) * rinv * g[t + 768] + b[t + 768]);
}

// ---------------- 128x128 GEMM: single 32KB LDS + reg prefetch dist 2 (R13, best) ----------
template <bool GELU, bool WF32, bool WBF16, int NRES, bool RES1B>
__global__ __launch_bounds__(256, 2) void k_g128r(
    const unsigned short* __restrict__ A, int lda,
    const unsigned short* __restrict__ W, int ldw,
    const float* __restrict__ bias,
    const float* __restrict__ res1, const unsigned short* __restrict__ res1b,
    const float* __restrict__ res2,
    float* __restrict__ outF, unsigned short* __restrict__ outB,
    int M, int N, int K, int nbx) {
  __shared__ unsigned short lds[16384];   // A[128][64] + B[128][64], one buffer (32KB)
  const int t = threadIdx.x;
  int tm, tn;
  map_tile(blockIdx.x, gridDim.x, nbx, tm, tn);
  const int tileM = tm * 128, tileN = tn * 128;
  const int lane = t & 63, w = t >> 6;
  const int wm = (w >> 1) * 64, wn = (w & 1) * 64;
  const int lr16 = lane & 15, kc4 = lane >> 4;

  const int sr = t >> 1, hb = t & 1;
  int gr = tileM + sr; if (gr >= M) gr = M - 1;
  const unsigned short* ga = A + (size_t)gr * lda + hb * 32;
  const unsigned short* gw = W + (size_t)(tileN + sr) * ldw + hb * 32;
  unsigned short* const wbA = &lds[sr * 64];
  const int wsl[4] = {((hb * 4 + 0) ^ (sr & 7)) * 8, ((hb * 4 + 1) ^ (sr & 7)) * 8,
                      ((hb * 4 + 2) ^ (sr & 7)) * 8, ((hb * 4 + 3) ^ (sr & 7)) * 8};

  f32x4 acc[4][4];
#pragma unroll
  for (int i = 0; i < 4; ++i)
#pragma unroll
    for (int j = 0; j < 4; ++j) acc[i][j] = f32x4{0.f, 0.f, 0.f, 0.f};

  const int nt = K >> 6;   // even for all ops here (K in {256,1024,4096})
  ushort8v raE[4], rbE[4], raO[4], rbO[4];

#define LOADT(T, ra, rb)                                      \
  do {                                                        \
    int ko = (T) << 6;                                        \
    _Pragma("unroll") for (int j = 0; j < 4; ++j) {           \
      ra[j] = *(const ushort8v*)(ga + ko + j * 8);            \
      rb[j] = *(const ushort8v*)(gw + ko + j * 8);            \
    }                                                         \
  } while (0)
#define WRITET(ra, rb)                                        \
  do {                                                        \
    _Pragma("unroll") for (int j = 0; j < 4; ++j) {           \
      *(ushort8v*)(wbA + wsl[j]) = ra[j];                     \
      *(ushort8v*)(wbA + 8192 + wsl[j]) = rb[j];              \
    }                                                         \
  } while (0)
#define COMPUTE()                                                               \
  do {                                                                          \
    _Pragma("unroll") for (int ks = 0; ks < 2; ++ks) {                          \
      short8v bfr[4];                                                           \
      _Pragma("unroll") for (int n = 0; n < 4; ++n) {                           \
        int r = wn + n * 16 + lr16;                                             \
        int sl = ((ks * 4 + kc4) ^ (r & 7)) * 8;                                \
        bfr[n] = *(const short8v*)&lds[8192 + r * 64 + sl];                     \
      }                                                                         \
      _Pragma("unroll") for (int mi = 0; mi < 4; ++mi) {                        \
        int r = wm + mi * 16 + lr16;                                            \
        int sl = ((ks * 4 + kc4) ^ (r & 7)) * 8;                                \
        short8v af = *(const short8v*)&lds[r * 64 + sl];                        \
        _Pragma("unroll") for (int n = 0; n < 4; ++n)                           \
          acc[mi][n] =                                                          \
              __builtin_amdgcn_mfma_f32_16x16x32_bf16(af, bfr[n], acc[mi][n], 0, 0, 0); \
      }                                                                         \
    }                                                                           \
  } while (0)

  LOADT(0, raE, rbE);
  WRITET(raE, rbE);
  if (nt > 1) LOADT(1, raO, rbO);
  __syncthreads();

  for (int T = 0; T < nt; T += 2) {
    if (T + 2 < nt) LOADT(T + 2, raE, rbE);
    COMPUTE();                        // tile T
    __syncthreads();                  // done reading tile T
    if (T + 1 < nt) {
      WRITET(raO, rbO);               // tile T+1 -> LDS
      if (T + 3 < nt) LOADT(T + 3, raO, rbO);
      __syncthreads();                // tile T+1 visible
      COMPUTE();                      // tile T+1
      __syncthreads();
      if (T + 2 < nt) WRITET(raE, rbE);
      __syncthreads();
    }
  }
#undef LOADT
#undef WRITET
#undef COMPUTE

#pragma unroll
  for (int mi = 0; mi < 4; ++mi) {
#pragma unroll
    for (int n = 0; n < 4; ++n) {
      int col = tileN + wn + n * 16 + lr16;
      float bv = bias[col];
#pragma unroll
      for (int qi = 0; qi < 4; ++qi) {
        int row = tileM + wm + mi * 16 + kc4 * 4 + qi;
        if (row < M) {
          float v = acc[mi][n][qi] + bv;
          if (GELU) v = gelu_f(v);
          size_t o = (size_t)row * N + col;
          if (NRES >= 1) v += RES1B ? b2f(res1b[o]) : res1[o];
          if (NRES >= 2) v += res2[o];
          if (WF32) outF[o] = v;
          if (WBF16) outB[o] = f2b(v);
        }
      }
    }
  }
}

// ---------------- V transpose: src[b*TB+tok][src_off+h*64+d] -> dst[bh][d][tok] ----------------
__global__ __launch_bounds__(256) void k_vtrans(const unsigned short* __restrict__ src,
                                                int src_stride, int src_off, int TB,
                                                unsigned short* __restrict__ dst, int dst_tstride) {
  __shared__ unsigned short tile[64][72];
  int tb = blockIdx.x, bh = blockIdx.y;
  int b = bh >> 4, h = bh & 15;
  int t = threadIdx.x;
  int r = t >> 2, c0 = (t & 3) * 16;
  int tok = tb * 64 + r; if (tok >= TB) tok = TB - 1;
  const unsigned short* s = src + (size_t)(b * TB + tok) * src_stride + src_off + h * 64 + c0;
  *(ushort8v*)&tile[r][c0] = *(const ushort8v*)s;
  *(ushort8v*)&tile[r][c0 + 8] = *(const ushort8v*)(s + 8);
  __syncthreads();
  unsigned short tmp[16];
#pragma unroll
  for (int j = 0; j < 16; ++j) tmp[j] = tile[c0 + j][r];
  unsigned short* dp = dst + ((size_t)bh * 64 + r) * dst_tstride + tb * 64 + c0;
  *(ushort8v*)dp = *(const ushort8v*)&tmp[0];
  *(ushort8v*)(dp + 8) = *(const ushort8v*)&tmp[8];
}

// ---------------- MFMA flash attention ----------------
template <bool CAUSAL>
__global__ __launch_bounds__(256) void k_attn(
    const unsigned short* __restrict__ Qb, int q_stride,
    const unsigned short* __restrict__ Kb, int k_stride, int k_off, int TKR,
    const unsigned short* __restrict__ Vt, int vt_tstride,
    unsigned short* __restrict__ out, int Tk) {
  __shared__ unsigned short Kl[64 * 72];
  __shared__ unsigned short Vl[64 * 72];
  __shared__ unsigned short Pl[4][16 * 72];
  const int swz = xcd_swz(blockIdx.x, gridDim.x);
  int qb = swz & 15, bh = swz >> 4;
  int b = bh >> 4, h = bh & 15;
  int t = threadIdx.x, lane = t & 63, w = t >> 6;
  int g = lane >> 4, lc = lane & 15;

  int qrow_g = qb * 64 + w * 16 + lc;
  const unsigned short* qp = Qb + (size_t)(b * 1024 + qrow_g) * q_stride + h * 64 + g * 8;
  short8v aq0 = *(const short8v*)qp;
  short8v aq1 = *(const short8v*)(qp + 32);

  f32x4 o[4];
  float m_[4], l_[4];
#pragma unroll
  for (int dt = 0; dt < 4; ++dt) o[dt] = f32x4{0.f, 0.f, 0.f, 0.f};
#pragma unroll
  for (int r = 0; r < 4; ++r) { m_[r] = -3.0e38f; l_[r] = 0.0f; }

  int srow = t >> 2;
  int sc = (t & 3) * 16;
  int ntiles = CAUSAL ? (qb + 1) : ((Tk + 63) >> 6);

  for (int kt = 0; kt < ntiles; ++kt) {
    __syncthreads();
    {
      int kg = kt * 64 + srow;
      if (!CAUSAL && kg >= Tk) kg = Tk - 1;
      const unsigned short* ks = Kb + (size_t)(b * TKR + kg) * k_stride + k_off + h * 64 + sc;
      *(ushort8v*)&Kl[srow * 72 + sc]     = *(const ushort8v*)ks;
      *(ushort8v*)&Kl[srow * 72 + sc + 8] = *(const ushort8v*)(ks + 8);
      const unsigned short* vs = Vt + ((size_t)bh * 64 + srow) * vt_tstride + kt * 64 + sc;
      *(ushort8v*)&Vl[srow * 72 + sc]     = *(const ushort8v*)vs;
      *(ushort8v*)&Vl[srow * 72 + sc + 8] = *(const ushort8v*)(vs + 8);
    }
    __syncthreads();

    f32x4 s[4];
#pragma unroll
    for (int jt = 0; jt < 4; ++jt) {
      short8v bk0 = *(const short8v*)&Kl[(jt * 16 + lc) * 72 + g * 8];
      short8v bk1 = *(const short8v*)&Kl[(jt * 16 + lc) * 72 + g * 8 + 32];
      f32x4 acc = f32x4{0.f, 0.f, 0.f, 0.f};
      acc = __builtin_amdgcn_mfma_f32_16x16x32_bf16(aq0, bk0, acc, 0, 0, 0);
      acc = __builtin_amdgcn_mfma_f32_16x16x32_bf16(aq1, bk1, acc, 0, 0, 0);
      s[jt] = acc;
    }
#pragma unroll
    for (int jt = 0; jt < 4; ++jt)
#pragma unroll
      for (int r = 0; r < 4; ++r) {
        float sv = s[jt][r] * 0.125f;
        bool masked = CAUSAL ? (kt == qb && (jt * 16 + lc) > (w * 16 + g * 4 + r))
                             : (kt * 64 + jt * 16 + lc >= Tk);
        s[jt][r] = masked ? -3.0e38f : sv;
      }
    float f[4];
#pragma unroll
    for (int r = 0; r < 4; ++r) {
      float mx = fmaxf(fmaxf(s[0][r], s[1][r]), fmaxf(s[2][r], s[3][r]));
      mx = fmaxf(mx, __shfl_xor(mx, 1));
      mx = fmaxf(mx, __shfl_xor(mx, 2));
      mx = fmaxf(mx, __shfl_xor(mx, 4));
      mx = fmaxf(mx, __shfl_xor(mx, 8));
      float mnew = fmaxf(m_[r], mx);
      f[r] = __expf(m_[r] - mnew);
      m_[r] = mnew;
      float rsum = 0.0f;
#pragma unroll
      for (int jt = 0; jt < 4; ++jt) {
        float p = __expf(s[jt][r] - mnew);
        s[jt][r] = p;
        rsum += p;
      }
      rsum += __shfl_xor(rsum, 1);
      rsum += __shfl_xor(rsum, 2);
      rsum += __shfl_xor(rsum, 4);
      rsum += __shfl_xor(rsum, 8);
      l_[r] = l_[r] * f[r] + rsum;
    }
#pragma unroll
    for (int dt = 0; dt < 4; ++dt)
#pragma unroll
      for (int r = 0; r < 4; ++r) o[dt][r] *= f[r];
#pragma unroll
    for (int jt = 0; jt < 4; ++jt)
#pragma unroll
      for (int r = 0; r < 4; ++r)
        Pl[w][(g * 4 + r) * 72 + jt * 16 + lc] = f2b(s[jt][r]);
    short8v ap0 = *(const short8v*)&Pl[w][lc * 72 + g * 8];
    short8v ap1 = *(const short8v*)&Pl[w][lc * 72 + g * 8 + 32];
#pragma unroll
    for (int dt = 0; dt < 4; ++dt) {
      short8v bv0 = *(const short8v*)&Vl[(dt * 16 + lc) * 72 + g * 8];
      short8v bv1 = *(const short8v*)&Vl[(dt * 16 + lc) * 72 + g * 8 + 32];
      o[dt] = __builtin_amdgcn_mfma_f32_16x16x32_bf16(ap0, bv0, o[dt], 0, 0, 0);
      o[dt] = __builtin_amdgcn_mfma_f32_16x16x32_bf16(ap1, bv1, o[dt], 0, 0, 0);
    }
  }
  size_t orow = (size_t)(b * 1024 + qb * 64 + w * 16) * 1024 + h * 64;
#pragma unroll
  for (int r = 0; r < 4; ++r) {
    float inv = 1.0f / l_[r];
#pragma unroll
    for (int dt = 0; dt < 4; ++dt)
      out[orow + (size_t)(g * 4 + r) * 1024 + dt * 16 + lc] = f2b(o[dt][r] * inv);
  }
}

extern "C" void kernel_launch(void* const* d_in, const int* in_sizes, int n_in,
                              void* d_out, int out_size, void* d_ws, size_t ws_size,
                              hipStream_t stream) {
  (void)in_sizes; (void)n_in; (void)out_size; (void)ws_size;
  const float* x       = (const float*)d_in[0];
  const float* enc     = (const float*)d_in[1];
  const float* ln1_g   = (const float*)d_in[3];
  const float* ln1_b   = (const float*)d_in[4];
  const float* ln2_g   = (const float*)d_in[5];
  const float* ln2_b   = (const float*)d_in[6];
  const float* ln3_g   = (const float*)d_in[7];
  const float* ln3_b   = (const float*)d_in[8];
  const float* attn_w  = (const float*)d_in[9];
  const float* attn_b  = (const float*)d_in[10];
  const float* aproj_w = (const float*)d_in[11];
  const float* aproj_b = (const float*)d_in[12];
  const float* ca_w    = (const float*)d_in[13];
  const float* ca_b    = (const float*)d_in[14];
  const float* caproj_w= (const float*)d_in[15];
  const float* caproj_b= (const float*)d_in[16];
  const float* fc_w    = (const float*)d_in[17];
  const float* fc_b    = (const float*)d_in[18];
  const float* mproj_w = (const float*)d_in[19];
  const float* mproj_b = (const float*)d_in[20];
  const float* down_w  = (const float*)d_in[21];
  const float* down_b  = (const float*)d_in[22];
  const float* up_w    = (const float*)d_in[23];
  const float* up_b    = (const float*)d_in[24];
  float* out = (float*)d_out;
  char* ws = (char*)d_ws;

  const size_t O_WATTN = 0, O_WAPROJ = 6291456, O_WCA = 8388608, O_WCAPROJ = 14680064,
               O_WFC = 16777216, O_WMPROJ = 25165824, O_WDOWN = 33554432, O_WUP = 34078720,
               O_ENC = 34603008, O_LN = 36708352, O_BIG = 45096960,
               O_XRES = 78651392, O_ATTN = 112205824;

  unsigned short* wt_attn   = (unsigned short*)(ws + O_WATTN);
  unsigned short* wt_aproj  = (unsigned short*)(ws + O_WAPROJ);
  unsigned short* wt_ca     = (unsigned short*)(ws + O_WCA);
  unsigned short* wt_caproj = (unsigned short*)(ws + O_WCAPROJ);
  unsigned short* wt_fc     = (unsigned short*)(ws + O_WFC);
  unsigned short* wt_mproj  = (unsigned short*)(ws + O_WMPROJ);
  unsigned short* wt_down   = (unsigned short*)(ws + O_WDOWN);
  unsigned short* wt_up     = (unsigned short*)(ws + O_WUP);
  unsigned short* encbf     = (unsigned short*)(ws + O_ENC);
  unsigned short* lnout     = (unsigned short*)(ws + O_LN);
  unsigned short* hbf       = (unsigned short*)(ws + O_LN);            // after fc consumed
  unsigned short* qkvb      = (unsigned short*)(ws + O_BIG);
  unsigned short* vt_self   = (unsigned short*)(ws + O_BIG + 25165824); // alive with qkvb
  unsigned short* q2b       = (unsigned short*)(ws + O_BIG);           // after self path done
  unsigned short* kvb       = (unsigned short*)(ws + O_BIG + 8388608);
  unsigned short* vt_cross  = (unsigned short*)(ws + O_BIG + 12599296);
  unsigned short* caout     = (unsigned short*)(ws + O_BIG + 15220736);
  unsigned short* fcout     = (unsigned short*)(ws + O_BIG);           // after cross path done
  float*          xres      = (float*)(ws + O_XRES);
  unsigned short* attnout   = (unsigned short*)(ws + O_ATTN);
  unsigned short* dmid      = (unsigned short*)(ws + O_ATTN);          // after aproj consumed

  dim3 blk(256);

  // 1. merged weight prep (8 transposes + enc cvt)
  k_wprep<<<dim3(5252), blk, 0, stream>>>(
      attn_w, wt_attn, aproj_w, wt_aproj, ca_w, wt_ca, caproj_w, wt_caproj,
      fc_w, wt_fc, mproj_w, wt_mproj, down_w, wt_down, up_w, wt_up, enc, encbf);

  // 3. ln1(x) ; qkv ; V-transpose ; self-attn ; aproj + residual(x) -> xres
  k_ln<<<dim3(4096), blk, 0, stream>>>(x, ln1_g, ln1_b, lnout);
  k_g128r<false, false, true, 0, false><<<dim3(768), blk, 0, stream>>>(
      lnout, 1024, wt_attn, 1024, attn_b, nullptr, nullptr, nullptr, nullptr, qkvb,
      4096, 3072, 1024, 24);
  k_vtrans<<<dim3(16, 64), blk, 0, stream>>>(qkvb, 3072, 2048, 1024, vt_self, 1024);
  k_attn<true><<<dim3(1024), blk, 0, stream>>>(
      qkvb, 3072, qkvb, 3072, 1024, 1024, vt_self, 1024, attnout, 1024);
  k_g128r<false, true, false, 1, false><<<dim3(256), blk, 0, stream>>>(
      attnout, 1024, wt_aproj, 1024, aproj_b, x, nullptr, nullptr, xres, nullptr,
      4096, 1024, 1024, 8);

  // 4. ln2(xres) ; q2 ; kv(enc) ; V-transpose ; cross-attn ; caproj + residual -> xres
  k_ln<<<dim3(4096), blk, 0, stream>>>(xres, ln2_g, ln2_b, lnout);
  k_g128r<false, false, true, 0, false><<<dim3(256), blk, 0, stream>>>(
      lnout, 1024, wt_ca, 1024, ca_b, nullptr, nullptr, nullptr, nullptr, q2b,
      4096, 1024, 1024, 8);
  k_g128r<false, false, true, 0, false><<<dim3(144), blk, 0, stream>>>(
      encbf, 1024, wt_ca + (size_t)1024 * 1024, 1024, ca_b + 1024, nullptr, nullptr,
      nullptr, nullptr, kvb, 1028, 2048, 1024, 16);
  k_vtrans<<<dim3(5, 64), blk, 0, stream>>>(kvb, 2048, 1024, 257, vt_cross, 320);
  k_attn<false><<<dim3(1024), blk, 0, stream>>>(
      q2b, 1024, kvb, 2048, 0, 257, vt_cross, 320, caout, 257);
  k_g128r<false, true, false, 1, false><<<dim3(256), blk, 0, stream>>>(
      caout, 1024, wt_caproj, 1024, caproj_b, xres, nullptr, nullptr, xres, nullptr,
      4096, 1024, 1024, 8);

  // 5. ln3(xres) ; fc+gelu ; mproj -> hbf
  k_ln<<<dim3(4096), blk, 0, stream>>>(xres, ln3_g, ln3_b, lnout);
  k_g128r<true, false, true, 0, false><<<dim3(1024), blk, 0, stream>>>(
      lnout, 1024, wt_fc, 1024, fc_b, nullptr, nullptr, nullptr, nullptr, fcout,
      4096, 4096, 1024, 32);
  k_g128r<false, false, true, 0, false><<<dim3(256), blk, 0, stream>>>(
      fcout, 4096, wt_mproj, 4096, mproj_b, nullptr, nullptr, nullptr, nullptr, hbf,
      4096, 1024, 4096, 8);

  // 6. adapter: down+gelu ; up + up_b + h(bf16) + xres -> out
  k_g128r<true, false, true, 0, false><<<dim3(64), blk, 0, stream>>>(
      hbf, 1024, wt_down, 1024, down_b, nullptr, nullptr, nullptr, nullptr, dmid,
      4096, 256, 1024, 2);
  k_g128r<false, true, false, 2, true><<<dim3(256), blk, 0, stream>>>(
      dmid, 256, wt_up, 256, up_b, nullptr, hbf, xres, out, nullptr,
      4096, 1024, 256, 8);
}

// Round 19
// 425.665 us; speedup vs baseline: 1.2270x; 1.0301x over previous
//
#include <hip/hip_runtime.h>

typedef __attribute__((ext_vector_type(8))) short short8v;
typedef __attribute__((ext_vector_type(8))) unsigned short ushort8v;
typedef __attribute__((ext_vector_type(4))) unsigned short ushort4v;
typedef __attribute__((ext_vector_type(4))) float f32x4;

__device__ __forceinline__ unsigned short f2b(float f) {
  unsigned int u = __float_as_uint(f);
  unsigned int r = (u + 0x7FFFu + ((u >> 16) & 1u)) >> 16;
  return (unsigned short)r;
}
__device__ __forceinline__ float b2f(unsigned short h) {
  return __uint_as_float(((unsigned int)h) << 16);
}
__device__ __forceinline__ float gelu_f(float x) {
  float z = 0.7978845608028654f * (x + 0.044715f * x * x * x);
  float e = __expf(2.0f * z);
  float t = 1.0f - 2.0f / (e + 1.0f);
  return 0.5f * x * (1.0f + t);
}
// bijective XCD swizzle (m204)
__device__ __forceinline__ int xcd_swz(int wgid, int nwg) {
  int q = nwg >> 3, r = nwg & 7;
  int xcd = wgid & 7, idx = wgid >> 3;
  return (xcd < r ? xcd * (q + 1) : r * (q + 1) + (xcd - r) * q) + idx;
}
// 2D XCD region mapping (fc FETCH 69.9->41.2 MB measured)
__device__ __forceinline__ void map_tile(int wgid, int nwg, int nbx, int& tm, int& tn) {
  int nby = nwg / nbx;
  if ((nwg & 7) == 0 && (nby & 3) == 0 && (nbx & 1) == 0) {
    int x = wgid & 7, idx = wgid >> 3;
    int rh = nby >> 2, rw = nbx >> 1;
    int xr = x >> 1, xc = x & 1;
    tm = xr * rh + idx / rw;
    tn = xc * rw + idx % rw;
  } else {
    int swz = xcd_swz(wgid, nwg);
    tm = swz / nbx;
    tn = swz % nbx;
  }
}

// ------ merged prep: 8 weight transposes + enc cvt + ln1 (independent of transposes) ------
__global__ __launch_bounds__(256) void k_wprep(
    const float* aw, unsigned short* awt,
    const float* apw, unsigned short* apwt,
    const float* cw, unsigned short* cwt,
    const float* cpw, unsigned short* cpwt,
    const float* fw, unsigned short* fwt,
    const float* mw, unsigned short* mwt,
    const float* dw, unsigned short* dwt,
    const float* uw, unsigned short* uwt,
    const float* enc, unsigned short* encb,
    const float* x, const float* g1, const float* b1, unsigned short* ln1out) {
  __shared__ float tile[64][65];
  __shared__ float rs[4], rs2[4];
  int bid = blockIdx.x, t = threadIdx.x;
  const float* w; unsigned short* wt; int K, N, gx, l;
  if      (bid < 768)  { w = aw;  wt = awt;  K = 1024; N = 3072; gx = 48; l = bid; }
  else if (bid < 1024) { w = apw; wt = apwt; K = 1024; N = 1024; gx = 16; l = bid - 768; }
  else if (bid < 1792) { w = cw;  wt = cwt;  K = 1024; N = 3072; gx = 48; l = bid - 1024; }
  else if (bid < 2048) { w = cpw; wt = cpwt; K = 1024; N = 1024; gx = 16; l = bid - 1792; }
  else if (bid < 3072) { w = fw;  wt = fwt;  K = 1024; N = 4096; gx = 64; l = bid - 2048; }
  else if (bid < 4096) { w = mw;  wt = mwt;  K = 4096; N = 1024; gx = 16; l = bid - 3072; }
  else if (bid < 4160) { w = dw;  wt = dwt;  K = 1024; N = 256;  gx = 4;  l = bid - 4096; }
  else if (bid < 4224) { w = uw;  wt = uwt;  K = 256;  N = 1024; gx = 16; l = bid - 4160; }
  else if (bid < 5252) {  // enc f32 -> bf16
    size_t i = ((size_t)(bid - 4224) * 256 + t) * 4;
    f32x4 v = *(const f32x4*)&enc[i];
    ushort4v o;
#pragma unroll
    for (int j = 0; j < 4; ++j) o[j] = f2b(v[j]);
    *(ushort4v*)&encb[i] = o;
    return;
  } else {                // ln1 row (independent of weight transposes)
    int row = bid - 5252;
    const float* xr = x + (size_t)row * 1024;
    float v0 = xr[t], v1 = xr[t + 256], v2 = xr[t + 512], v3 = xr[t + 768];
    float s = v0 + v1 + v2 + v3;
    float s2 = v0 * v0 + v1 * v1 + v2 * v2 + v3 * v3;
#pragma unroll
    for (int m = 1; m < 64; m <<= 1) { s += __shfl_xor(s, m); s2 += __shfl_xor(s2, m); }
    int wv = t >> 6;
    if ((t & 63) == 0) { rs[wv] = s; rs2[wv] = s2; }
    __syncthreads();
    s = rs[0] + rs[1] + rs[2] + rs[3];
    s2 = rs2[0] + rs2[1] + rs2[2] + rs2[3];
    float mean = s * (1.0f / 1024.0f);
    float var = s2 * (1.0f / 1024.0f) - mean * mean;
    float rinv = rsqrtf(var + 1e-5f);
    unsigned short* o = ln1out + (size_t)row * 1024;
    o[t]       = f2b((v0 - mean) * rinv * g1[t]       + b1[t]);
    o[t + 256] = f2b((v1 - mean) * rinv * g1[t + 256] + b1[t + 256]);
    o[t + 512] = f2b((v2 - mean) * rinv * g1[t + 512] + b1[t + 512]);
    o[t + 768] = f2b((v3 - mean) * rinv * g1[t + 768] + b1[t + 768]);
    return;
  }
  int bx = l % gx, by = l / gx;
  int tn = bx * 64, tk = by * 64;
  int c = t & 63, r0 = t >> 6;
#pragma unroll
  for (int p = 0; p < 16; ++p) {
    int r = r0 + p * 4;
    tile[r][c] = w[(size_t)(tk + r) * N + tn + c];
  }
  __syncthreads();
#pragma unroll
  for (int p = 0; p < 16; ++p) {
    int r = r0 + p * 4;
    wt[(size_t)(tn + r) * K + tk + c] = f2b(tile[c][r]);
  }
}

// ---------------- LayerNorm over C=1024, out bf16 ----------------
__global__ __launch_bounds__(256) void k_ln(const float* __restrict__ in,
                                            const float* __restrict__ g,
                                            const float* __restrict__ b,
                                            unsigned short* __restrict__ out) {
  int row = blockIdx.x;
  const float* x = in + (size_t)row * 1024;
  int t = threadIdx.x;
  float v0 = x[t], v1 = x[t + 256], v2 = x[t + 512], v3 = x[t + 768];
  float s = v0 + v1 + v2 + v3;
  float s2 = v0 * v0 + v1 * v1 + v2 * v2 + v3 * v3;
#pragma unroll
  for (int m = 1; m < 64; m <<= 1) { s += __shfl_xor(s, m); s2 += __shfl_xor(s2, m); }
  __shared__ float rs[4], rs2[4];
  int w = t >> 6;
  if ((t & 63) == 0) { rs[w] = s; rs2[w] = s2; }
  __syncthreads();
  s = rs[0] + rs[1] + rs[2] + rs[3];
  s2 = rs2[0] + rs2[1] + rs2[2] + rs2[3];
  float mean = s * (1.0f / 1024.0f);
  float var = s2 * (1.0f / 1024.0f) - mean * mean;
  float rinv = rsqrtf(var + 1e-5f);
  unsigned short* o = out + (size_t)row * 1024;
  o[t]       = f2b((v0 - mean) * rinv * g[t]       + b[t]);
  o[t + 256] = f2b((v1 - mean) * rinv * g[t + 256] + b[t + 256]);
  o[t + 512] = f2b((v2 - mean) * rinv * g[t + 512] + b[t + 512]);
  o[t + 768] = f2b((v3 - mean) * rinv * g[t + 768] + b[t + 768]);
}

// ---------------- 128x128 GEMM: single 32KB LDS + reg prefetch dist 2 (R13, best) ----------
// Dual mode (nsplit>0): blocks < nsplit run param-set 1, others set 2 (independent GEMMs
// fused into one dispatch; per-segment wgid/nwg keep tile maps identical to split launches).
template <bool GELU, bool WF32, bool WBF16, int NRES, bool RES1B>
__global__ __launch_bounds__(256, 2) void k_g128r(
    const unsigned short* __restrict__ A_, int lda,
    const unsigned short* __restrict__ W_, int ldw,
    const float* __restrict__ bias_,
    const float* __restrict__ res1, const unsigned short* __restrict__ res1b,
    const float* __restrict__ res2,
    float* __restrict__ outF, unsigned short* __restrict__ outB_,
    int M_, int N_, int K, int nbx_,
    const unsigned short* A2, const unsigned short* W2, const float* bias2,
    unsigned short* outB2, int M2, int N2, int nbx2, int nsplit) {
  __shared__ unsigned short lds[16384];   // A[128][64] + B[128][64], one buffer (32KB)
  const int t = threadIdx.x;
  const unsigned short* A = A_;
  const unsigned short* W = W_;
  const float* bias = bias_;
  unsigned short* outB = outB_;
  int M = M_, N = N_, nbx = nbx_;
  int wgid = blockIdx.x, nwg = gridDim.x;
  if (nsplit > 0) {
    if (blockIdx.x >= nsplit) {
      A = A2; W = W2; bias = bias2; outB = outB2;
      M = M2; N = N2; nbx = nbx2;
      wgid = blockIdx.x - nsplit; nwg = gridDim.x - nsplit;
    } else {
      nwg = nsplit;
    }
  }
  int tm, tn;
  map_tile(wgid, nwg, nbx, tm, tn);
  const int tileM = tm * 128, tileN = tn * 128;
  const int lane = t & 63, w = t >> 6;
  const int wm = (w >> 1) * 64, wn = (w & 1) * 64;
  const int lr16 = lane & 15, kc4 = lane >> 4;

  const int sr = t >> 1, hb = t & 1;
  int gr = tileM + sr; if (gr >= M) gr = M - 1;
  const unsigned short* ga = A + (size_t)gr * lda + hb * 32;
  const unsigned short* gw = W + (size_t)(tileN + sr) * ldw + hb * 32;
  unsigned short* const wbA = &lds[sr * 64];
  const int wsl[4] = {((hb * 4 + 0) ^ (sr & 7)) * 8, ((hb * 4 + 1) ^ (sr & 7)) * 8,
                      ((hb * 4 + 2) ^ (sr & 7)) * 8, ((hb * 4 + 3) ^ (sr & 7)) * 8};

  f32x4 acc[4][4];
#pragma unroll
  for (int i = 0; i < 4; ++i)
#pragma unroll
    for (int j = 0; j < 4; ++j) acc[i][j] = f32x4{0.f, 0.f, 0.f, 0.f};

  const int nt = K >> 6;   // even for all ops here (K in {256,1024,4096})
  ushort8v raE[4], rbE[4], raO[4], rbO[4];

#define LOADT(T, ra, rb)                                      \
  do {                                                        \
    int ko = (T) << 6;                                        \
    _Pragma("unroll") for (int j = 0; j < 4; ++j) {           \
      ra[j] = *(const ushort8v*)(ga + ko + j * 8);            \
      rb[j] = *(const ushort8v*)(gw + ko + j * 8);            \
    }                                                         \
  } while (0)
#define WRITET(ra, rb)                                        \
  do {                                                        \
    _Pragma("unroll") for (int j = 0; j < 4; ++j) {           \
      *(ushort8v*)(wbA + wsl[j]) = ra[j];                     \
      *(ushort8v*)(wbA + 8192 + wsl[j]) = rb[j];              \
    }                                                         \
  } while (0)
#define COMPUTE()                                                               \
  do {                                                                          \
    _Pragma("unroll") for (int ks = 0; ks < 2; ++ks) {                          \
      short8v bfr[4];                                                           \
      _Pragma("unroll") for (int n = 0; n < 4; ++n) {                           \
        int r = wn + n * 16 + lr16;                                             \
        int sl = ((ks * 4 + kc4) ^ (r & 7)) * 8;                                \
        bfr[n] = *(const short8v*)&lds[8192 + r * 64 + sl];                     \
      }                                                                         \
      _Pragma("unroll") for (int mi = 0; mi < 4; ++mi) {                        \
        int r = wm + mi * 16 + lr16;                                            \
        int sl = ((ks * 4 + kc4) ^ (r & 7)) * 8;                                \
        short8v af = *(const short8v*)&lds[r * 64 + sl];                        \
        _Pragma("unroll") for (int n = 0; n < 4; ++n)                           \
          acc[mi][n] =                                                          \
              __builtin_amdgcn_mfma_f32_16x16x32_bf16(af, bfr[n], acc[mi][n], 0, 0, 0); \
      }                                                                         \
    }                                                                           \
  } while (0)

  LOADT(0, raE, rbE);
  WRITET(raE, rbE);
  if (nt > 1) LOADT(1, raO, rbO);
  __syncthreads();

  for (int T = 0; T < nt; T += 2) {
    if (T + 2 < nt) LOADT(T + 2, raE, rbE);
    COMPUTE();                        // tile T
    __syncthreads();                  // done reading tile T
    if (T + 1 < nt) {
      WRITET(raO, rbO);               // tile T+1 -> LDS
      if (T + 3 < nt) LOADT(T + 3, raO, rbO);
      __syncthreads();                // tile T+1 visible
      COMPUTE();                      // tile T+1
      __syncthreads();
      if (T + 2 < nt) WRITET(raE, rbE);
      __syncthreads();
    }
  }
#undef LOADT
#undef WRITET
#undef COMPUTE

#pragma unroll
  for (int mi = 0; mi < 4; ++mi) {
#pragma unroll
    for (int n = 0; n < 4; ++n) {
      int col = tileN + wn + n * 16 + lr16;
      float bv = bias[col];
#pragma unroll
      for (int qi = 0; qi < 4; ++qi) {
        int row = tileM + wm + mi * 16 + kc4 * 4 + qi;
        if (row < M) {
          float v = acc[mi][n][qi] + bv;
          if (GELU) v = gelu_f(v);
          size_t o = (size_t)row * N + col;
          if (NRES >= 1) v += RES1B ? b2f(res1b[o]) : res1[o];
          if (NRES >= 2) v += res2[o];
          if (WF32) outF[o] = v;
          if (WBF16) outB[o] = f2b(v);
        }
      }
    }
  }
}

// ---------------- V transpose: src[b*TB+tok][src_off+h*64+d] -> dst[bh][d][tok] ----------------
__global__ __launch_bounds__(256) void k_vtrans(const unsigned short* __restrict__ src,
                                                int src_stride, int src_off, int TB,
                                                unsigned short* __restrict__ dst, int dst_tstride) {
  __shared__ unsigned short tile[64][72];
  int tb = blockIdx.x, bh = blockIdx.y;
  int b = bh >> 4, h = bh & 15;
  int t = threadIdx.x;
  int r = t >> 2, c0 = (t & 3) * 16;
  int tok = tb * 64 + r; if (tok >= TB) tok = TB - 1;
  const unsigned short* s = src + (size_t)(b * TB + tok) * src_stride + src_off + h * 64 + c0;
  *(ushort8v*)&tile[r][c0] = *(const ushort8v*)s;
  *(ushort8v*)&tile[r][c0 + 8] = *(const ushort8v*)(s + 8);
  __syncthreads();
  unsigned short tmp[16];
#pragma unroll
  for (int j = 0; j < 16; ++j) tmp[j] = tile[c0 + j][r];
  unsigned short* dp = dst + ((size_t)bh * 64 + r) * dst_tstride + tb * 64 + c0;
  *(ushort8v*)dp = *(const ushort8v*)&tmp[0];
  *(ushort8v*)(dp + 8) = *(const ushort8v*)&tmp[8];
}

// ---------------- MFMA flash attention ----------------
template <bool CAUSAL>
__global__ __launch_bounds__(256) void k_attn(
    const unsigned short* __restrict__ Qb, int q_stride,
    const unsigned short* __restrict__ Kb, int k_stride, int k_off, int TKR,
    const unsigned short* __restrict__ Vt, int vt_tstride,
    unsigned short* __restrict__ out, int Tk) {
  __shared__ unsigned short Kl[64 * 72];
  __shared__ unsigned short Vl[64 * 72];
  __shared__ unsigned short Pl[4][16 * 72];
  const int swz = xcd_swz(blockIdx.x, gridDim.x);
  int qb = swz & 15, bh = swz >> 4;
  int b = bh >> 4, h = bh & 15;
  int t = threadIdx.x, lane = t & 63, w = t >> 6;
  int g = lane >> 4, lc = lane & 15;

  int qrow_g = qb * 64 + w * 16 + lc;
  const unsigned short* qp = Qb + (size_t)(b * 1024 + qrow_g) * q_stride + h * 64 + g * 8;
  short8v aq0 = *(const short8v*)qp;
  short8v aq1 = *(const short8v*)(qp + 32);

  f32x4 o[4];
  float m_[4], l_[4];
#pragma unroll
  for (int dt = 0; dt < 4; ++dt) o[dt] = f32x4{0.f, 0.f, 0.f, 0.f};
#pragma unroll
  for (int r = 0; r < 4; ++r) { m_[r] = -3.0e38f; l_[r] = 0.0f; }

  int srow = t >> 2;
  int sc = (t & 3) * 16;
  int ntiles = CAUSAL ? (qb + 1) : ((Tk + 63) >> 6);

  for (int kt = 0; kt < ntiles; ++kt) {
    __syncthreads();
    {
      int kg = kt * 64 + srow;
      if (!CAUSAL && kg >= Tk) kg = Tk - 1;
      const unsigned short* ks = Kb + (size_t)(b * TKR + kg) * k_stride + k_off + h * 64 + sc;
      *(ushort8v*)&Kl[srow * 72 + sc]     = *(const ushort8v*)ks;
      *(ushort8v*)&Kl[srow * 72 + sc + 8] = *(const ushort8v*)(ks + 8);
      const unsigned short* vs = Vt + ((size_t)bh * 64 + srow) * vt_tstride + kt * 64 + sc;
      *(ushort8v*)&Vl[srow * 72 + sc]     = *(const ushort8v*)vs;
      *(ushort8v*)&Vl[srow * 72 + sc + 8] = *(const ushort8v*)(vs + 8);
    }
    __syncthreads();

    f32x4 s[4];
#pragma unroll
    for (int jt = 0; jt < 4; ++jt) {
      short8v bk0 = *(const short8v*)&Kl[(jt * 16 + lc) * 72 + g * 8];
      short8v bk1 = *(const short8v*)&Kl[(jt * 16 + lc) * 72 + g * 8 + 32];
      f32x4 acc = f32x4{0.f, 0.f, 0.f, 0.f};
      acc = __builtin_amdgcn_mfma_f32_16x16x32_bf16(aq0, bk0, acc, 0, 0, 0);
      acc = __builtin_amdgcn_mfma_f32_16x16x32_bf16(aq1, bk1, acc, 0, 0, 0);
      s[jt] = acc;
    }
#pragma unroll
    for (int jt = 0; jt < 4; ++jt)
#pragma unroll
      for (int r = 0; r < 4; ++r) {
        float sv = s[jt][r] * 0.125f;
        bool masked = CAUSAL ? (kt == qb && (jt * 16 + lc) > (w * 16 + g * 4 + r))
                             : (kt * 64 + jt * 16 + lc >= Tk);
        s[jt][r] = masked ? -3.0e38f : sv;
      }
    float f[4];
#pragma unroll
    for (int r = 0; r < 4; ++r) {
      float mx = fmaxf(fmaxf(s[0][r], s[1][r]), fmaxf(s[2][r], s[3][r]));
      mx = fmaxf(mx, __shfl_xor(mx, 1));
      mx = fmaxf(mx, __shfl_xor(mx, 2));
      mx = fmaxf(mx, __shfl_xor(mx, 4));
      mx = fmaxf(mx, __shfl_xor(mx, 8));
      float mnew = fmaxf(m_[r], mx);
      f[r] = __expf(m_[r] - mnew);
      m_[r] = mnew;
      float rsum = 0.0f;
#pragma unroll
      for (int jt = 0; jt < 4; ++jt) {
        float p = __expf(s[jt][r] - mnew);
        s[jt][r] = p;
        rsum += p;
      }
      rsum += __shfl_xor(rsum, 1);
      rsum += __shfl_xor(rsum, 2);
      rsum += __shfl_xor(rsum, 4);
      rsum += __shfl_xor(rsum, 8);
      l_[r] = l_[r] * f[r] + rsum;
    }
#pragma unroll
    for (int dt = 0; dt < 4; ++dt)
#pragma unroll
      for (int r = 0; r < 4; ++r) o[dt][r] *= f[r];
#pragma unroll
    for (int jt = 0; jt < 4; ++jt)
#pragma unroll
      for (int r = 0; r < 4; ++r)
        Pl[w][(g * 4 + r) * 72 + jt * 16 + lc] = f2b(s[jt][r]);
    short8v ap0 = *(const short8v*)&Pl[w][lc * 72 + g * 8];
    short8v ap1 = *(const short8v*)&Pl[w][lc * 72 + g * 8 + 32];
#pragma unroll
    for (int dt = 0; dt < 4; ++dt) {
      short8v bv0 = *(const short8v*)&Vl[(dt * 16 + lc) * 72 + g * 8];
      short8v bv1 = *(const short8v*)&Vl[(dt * 16 + lc) * 72 + g * 8 + 32];
      o[dt] = __builtin_amdgcn_mfma_f32_16x16x32_bf16(ap0, bv0, o[dt], 0, 0, 0);
      o[dt] = __builtin_amdgcn_mfma_f32_16x16x32_bf16(ap1, bv1, o[dt], 0, 0, 0);
    }
  }
  size_t orow = (size_t)(b * 1024 + qb * 64 + w * 16) * 1024 + h * 64;
#pragma unroll
  for (int r = 0; r < 4; ++r) {
    float inv = 1.0f / l_[r];
#pragma unroll
    for (int dt = 0; dt < 4; ++dt)
      out[orow + (size_t)(g * 4 + r) * 1024 + dt * 16 + lc] = f2b(o[dt][r] * inv);
  }
}

extern "C" void kernel_launch(void* const* d_in, const int* in_sizes, int n_in,
                              void* d_out, int out_size, void* d_ws, size_t ws_size,
                              hipStream_t stream) {
  (void)in_sizes; (void)n_in; (void)out_size; (void)ws_size;
  const float* x       = (const float*)d_in[0];
  const float* enc     = (const float*)d_in[1];
  const float* ln1_g   = (const float*)d_in[3];
  const float* ln1_b   = (const float*)d_in[4];
  const float* ln2_g   = (const float*)d_in[5];
  const float* ln2_b   = (const float*)d_in[6];
  const float* ln3_g   = (const float*)d_in[7];
  const float* ln3_b   = (const float*)d_in[8];
  const float* attn_w  = (const float*)d_in[9];
  const float* attn_b  = (const float*)d_in[10];
  const float* aproj_w = (const float*)d_in[11];
  const float* aproj_b = (const float*)d_in[12];
  const float* ca_w    = (const float*)d_in[13];
  const float* ca_b    = (const float*)d_in[14];
  const float* caproj_w= (const float*)d_in[15];
  const float* caproj_b= (const float*)d_in[16];
  const float* fc_w    = (const float*)d_in[17];
  const float* fc_b    = (const float*)d_in[18];
  const float* mproj_w = (const float*)d_in[19];
  const float* mproj_b = (const float*)d_in[20];
  const float* down_w  = (const float*)d_in[21];
  const float* down_b  = (const float*)d_in[22];
  const float* up_w    = (const float*)d_in[23];
  const float* up_b    = (const float*)d_in[24];
  float* out = (float*)d_out;
  char* ws = (char*)d_ws;

  const size_t O_WATTN = 0, O_WAPROJ = 6291456, O_WCA = 8388608, O_WCAPROJ = 14680064,
               O_WFC = 16777216, O_WMPROJ = 25165824, O_WDOWN = 33554432, O_WUP = 34078720,
               O_ENC = 34603008, O_LN = 36708352, O_BIG = 45096960,
               O_XRES = 78651392, O_ATTN = 112205824;

  unsigned short* wt_attn   = (unsigned short*)(ws + O_WATTN);
  unsigned short* wt_aproj  = (unsigned short*)(ws + O_WAPROJ);
  unsigned short* wt_ca     = (unsigned short*)(ws + O_WCA);
  unsigned short* wt_caproj = (unsigned short*)(ws + O_WCAPROJ);
  unsigned short* wt_fc     = (unsigned short*)(ws + O_WFC);
  unsigned short* wt_mproj  = (unsigned short*)(ws + O_WMPROJ);
  unsigned short* wt_down   = (unsigned short*)(ws + O_WDOWN);
  unsigned short* wt_up     = (unsigned short*)(ws + O_WUP);
  unsigned short* encbf     = (unsigned short*)(ws + O_ENC);
  unsigned short* lnout     = (unsigned short*)(ws + O_LN);
  unsigned short* hbf       = (unsigned short*)(ws + O_LN);            // after fc consumed
  unsigned short* qkvb      = (unsigned short*)(ws + O_BIG);
  unsigned short* vt_self   = (unsigned short*)(ws + O_BIG + 25165824); // alive with qkvb
  unsigned short* q2b       = (unsigned short*)(ws + O_BIG);           // after self path done
  unsigned short* kvb       = (unsigned short*)(ws + O_BIG + 8388608);
  unsigned short* vt_cross  = (unsigned short*)(ws + O_BIG + 12599296);
  unsigned short* caout     = (unsigned short*)(ws + O_BIG + 15220736);
  unsigned short* fcout     = (unsigned short*)(ws + O_BIG);           // after cross path done
  float*          xres      = (float*)(ws + O_XRES);
  unsigned short* attnout   = (unsigned short*)(ws + O_ATTN);
  unsigned short* dmid      = (unsigned short*)(ws + O_ATTN);          // after aproj consumed

  dim3 blk(256);

  // 1. merged prep: 8 weight transposes + enc cvt + ln1 (independent work, one dispatch)
  k_wprep<<<dim3(9348), blk, 0, stream>>>(
      attn_w, wt_attn, aproj_w, wt_aproj, ca_w, wt_ca, caproj_w, wt_caproj,
      fc_w, wt_fc, mproj_w, wt_mproj, down_w, wt_down, up_w, wt_up, enc, encbf,
      x, ln1_g, ln1_b, lnout);

  // 3. qkv ; V-transpose ; self-attn ; aproj + residual(x) -> xres
  k_g128r<false, false, true, 0, false><<<dim3(768), blk, 0, stream>>>(
      lnout, 1024, wt_attn, 1024, attn_b, nullptr, nullptr, nullptr, nullptr, qkvb,
      4096, 3072, 1024, 24,
      nullptr, nullptr, nullptr, nullptr, 0, 0, 0, 0);
  k_vtrans<<<dim3(16, 64), blk, 0, stream>>>(qkvb, 3072, 2048, 1024, vt_self, 1024);
  k_attn<true><<<dim3(1024), blk, 0, stream>>>(
      qkvb, 3072, qkvb, 3072, 1024, 1024, vt_self, 1024, attnout, 1024);
  k_g128r<false, true, false, 1, false><<<dim3(256), blk, 0, stream>>>(
      attnout, 1024, wt_aproj, 1024, aproj_b, x, nullptr, nullptr, xres, nullptr,
      4096, 1024, 1024, 8,
      nullptr, nullptr, nullptr, nullptr, 0, 0, 0, 0);

  // 4. ln2(xres) ; fused {q2 | kv(enc)} ; V-transpose ; cross-attn ; caproj + residual -> xres
  k_ln<<<dim3(4096), blk, 0, stream>>>(xres, ln2_g, ln2_b, lnout);
  k_g128r<false, false, true, 0, false><<<dim3(400), blk, 0, stream>>>(
      lnout, 1024, wt_ca, 1024, ca_b, nullptr, nullptr, nullptr, nullptr, q2b,
      4096, 1024, 1024, 8,
      encbf, wt_ca + (size_t)1024 * 1024, ca_b + 1024, kvb, 1028, 2048, 16, 256);
  k_vtrans<<<dim3(5, 64), blk, 0, stream>>>(kvb, 2048, 1024, 257, vt_cross, 320);
  k_attn<false><<<dim3(1024), blk, 0, stream>>>(
      q2b, 1024, kvb, 2048, 0, 257, vt_cross, 320, caout, 257);
  k_g128r<false, true, false, 1, false><<<dim3(256), blk, 0, stream>>>(
      caout, 1024, wt_caproj, 1024, caproj_b, xres, nullptr, nullptr, xres, nullptr,
      4096, 1024, 1024, 8,
      nullptr, nullptr, nullptr, nullptr, 0, 0, 0, 0);

  // 5. ln3(xres) ; fc+gelu ; mproj -> hbf
  k_ln<<<dim3(4096), blk, 0, stream>>>(xres, ln3_g, ln3_b, lnout);
  k_g128r<true, false, true, 0, false><<<dim3(1024), blk, 0, stream>>>(
      lnout, 1024, wt_fc, 1024, fc_b, nullptr, nullptr, nullptr, nullptr, fcout,
      4096, 4096, 1024, 32,
      nullptr, nullptr, nullptr, nullptr, 0, 0, 0, 0);
  k_g128r<false, false, true, 0, false><<<dim3(256), blk, 0, stream>>>(
      fcout, 4096, wt_mproj, 4096, mproj_b, nullptr, nullptr, nullptr, nullptr, hbf,
      4096, 1024, 4096, 8,
      nullptr, nullptr, nullptr, nullptr, 0, 0, 0, 0);

  // 6. adapter: down+gelu ; up + up_b + h(bf16) + xres -> out
  k_g128r<true, false, true, 0, false><<<dim3(64), blk, 0, stream>>>(
      hbf, 1024, wt_down, 1024, down_b, nullptr, nullptr, nullptr, nullptr, dmid,
      4096, 256, 1024, 2,
      nullptr, nullptr, nullptr, nullptr, 0, 0, 0, 0);
  k_g128r<false, true, false, 2, true><<<dim3(256), blk, 0, stream>>>(
      dmid, 256, wt_up, 256, up_b, nullptr, hbf, xres, out, nullptr,
      4096, 1024, 256, 8,
      nullptr, nullptr, nullptr, nullptr, 0, 0, 0, 0);
}